// Round 1
// baseline (2457.539 us; speedup 1.0000x reference)
//
#include <hip/hip_runtime.h>
#include <hip/hip_bf16.h>
#include <math.h>

#define TB 16
#define TS 512
#define TD 768
#define TH 3072
#define TNH 12
#define TE 7
#define TT (TB*TS)  // 8192 tokens

typedef __bf16 bf16x8_t __attribute__((ext_vector_type(8)));
typedef float f32x4_t __attribute__((ext_vector_type(4)));

#define NEGINF (-__builtin_huge_valf())

// ---------------- block reduction helper (256 threads, 4 waves) ----------------
__device__ __forceinline__ float block_sum256(float v, float* red4) {
  #pragma unroll
  for (int o = 32; o > 0; o >>= 1) v += __shfl_down(v, o, 64);
  int lane = threadIdx.x & 63, wv = threadIdx.x >> 6;
  if (lane == 0) red4[wv] = v;
  __syncthreads();
  float r = red4[0] + red4[1] + red4[2] + red4[3];
  __syncthreads();
  return r;
}

// ---------------- LN1: hidden -> x1 (fp32) ----------------
__global__ __launch_bounds__(256) void ln1_k(const float* __restrict__ in,
                                             const float* __restrict__ g,
                                             const float* __restrict__ bb,
                                             float* __restrict__ out) {
  __shared__ float red4[4];
  int row = blockIdx.x, tid = threadIdx.x;
  const float* x = in + (size_t)row * TD;
  float v0 = x[tid], v1 = x[tid + 256], v2 = x[tid + 512];
  float sum = block_sum256(v0 + v1 + v2, red4);
  float mean = sum * (1.0f / 768.0f);
  float d0 = v0 - mean, d1 = v1 - mean, d2 = v2 - mean;
  float var = block_sum256(d0*d0 + d1*d1 + d2*d2, red4) * (1.0f / 768.0f);
  float rs = rsqrtf(var + 1e-12f);
  float* o = out + (size_t)row * TD;
  o[tid]       = g[tid]       * (d0 * rs) + bb[tid];
  o[tid + 256] = g[tid + 256] * (d1 * rs) + bb[tid + 256];
  o[tid + 512] = g[tid + 512] * (d2 * rs) + bb[tid + 512];
}

// ---------------- fp32 GEMM, 128x128 tile, BK=8 ----------------
// EPI==0: QKV fused  (B selected from B0/B1/B2 by column block; q scaled 0.125)
// EPI==1: O-proj + bias + residual
template<int EPI>
__global__ __launch_bounds__(256) void gemm_f32k(
    const float* __restrict__ A, int lda,
    const float* __restrict__ B0, const float* __restrict__ B1, const float* __restrict__ B2,
    const float* __restrict__ bi0, const float* __restrict__ bi1, const float* __restrict__ bi2,
    const float* __restrict__ resid,
    float* __restrict__ Cout, int ldc, int Kdim)
{
  __shared__ float As[8][132];   // transposed: As[k][m]
  __shared__ float Bs[8][128];   // Bs[k][n]
  int n0 = blockIdx.x * 128, m0 = blockIdx.y * 128;
  const float* Bp = B0; const float* bp = bi0; float scale = 1.0f; int nloc = n0;
  if (EPI == 0) {
    int sel = n0 / 768; nloc = n0 - sel * 768;
    Bp = (sel == 0) ? B0 : (sel == 1) ? B1 : B2;
    bp = (sel == 0) ? bi0 : (sel == 1) ? bi1 : bi2;
    scale = (sel == 0) ? 0.125f : 1.0f;
  }
  int tid = threadIdx.x;
  int tx = tid & 15, ty = tid >> 4;
  float acc[8][8] = {};
  for (int k0 = 0; k0 < Kdim; k0 += 8) {
    {
      int r = tid >> 1, c = (tid & 1) * 4;
      float4 av = *(const float4*)(A + (size_t)(m0 + r) * lda + k0 + c);
      As[c + 0][r] = av.x; As[c + 1][r] = av.y; As[c + 2][r] = av.z; As[c + 3][r] = av.w;
      int rb = tid >> 5, cb = (tid & 31) * 4;
      *(float4*)&Bs[rb][cb] = *(const float4*)(Bp + (size_t)(k0 + rb) * 768 + nloc + cb);
    }
    __syncthreads();
    #pragma unroll
    for (int kk = 0; kk < 8; ++kk) {
      float a[8], b[8];
      #pragma unroll
      for (int j = 0; j < 8; ++j) { a[j] = As[kk][ty + 16 * j]; b[j] = Bs[kk][tx + 16 * j]; }
      #pragma unroll
      for (int im = 0; im < 8; ++im)
        #pragma unroll
        for (int jn = 0; jn < 8; ++jn) acc[im][jn] += a[im] * b[jn];
    }
    __syncthreads();
  }
  #pragma unroll
  for (int im = 0; im < 8; ++im) {
    int row = m0 + ty + 16 * im;
    #pragma unroll
    for (int jn = 0; jn < 8; ++jn) {
      int colg = n0 + tx + 16 * jn;
      int coll = nloc + tx + 16 * jn;
      float v = acc[im][jn] + bp[coll];
      if (EPI == 0) v *= scale;
      else          v += resid[(size_t)row * 768 + colg];
      Cout[(size_t)row * ldc + colg] = v;
    }
  }
}

// ---------------- fp32 flash attention ----------------
// grid (8 qtiles, 12 heads, 16 batch), 256 threads. qkv: [T][2304] (q|k|v), q pre-scaled.
__global__ __launch_bounds__(256) void attn_k(const float* __restrict__ qkv,
                                              const int* __restrict__ mask,
                                              float* __restrict__ ctx) {
  __shared__ float Qs[64][65];
  __shared__ float Ks[32][65];
  __shared__ float Vs[32][65];
  __shared__ float Ps[64][33];
  __shared__ float tmaxs[64][4];
  __shared__ float tsums[64][4];
  __shared__ float mrow[64], lrow[64];
  int qt = blockIdx.x, h = blockIdx.y, b = blockIdx.z;
  int tid = threadIdx.x;
  int ql = tid & 63, quad = tid >> 6;
  const size_t rowbase = (size_t)(b * TS) * 2304 + h * 64;
  for (int f = tid; f < 64 * 16; f += 256) {
    int r = f >> 4, c4 = (f & 15) * 4;
    float4 v = *(const float4*)(qkv + rowbase + (size_t)(qt * 64 + r) * 2304 + c4);
    Qs[r][c4 + 0] = v.x; Qs[r][c4 + 1] = v.y; Qs[r][c4 + 2] = v.z; Qs[r][c4 + 3] = v.w;
  }
  if (tid < 64) { mrow[tid] = NEGINF; lrow[tid] = 0.0f; }
  float accv[16];
  #pragma unroll
  for (int i = 0; i < 16; ++i) accv[i] = 0.0f;
  __syncthreads();
  for (int kc = 0; kc < 16; ++kc) {
    for (int f = tid; f < 32 * 16; f += 256) {
      int r = f >> 4, c4 = (f & 15) * 4;
      float4 kv = *(const float4*)(qkv + rowbase + 768 + (size_t)(kc * 32 + r) * 2304 + c4);
      Ks[r][c4 + 0] = kv.x; Ks[r][c4 + 1] = kv.y; Ks[r][c4 + 2] = kv.z; Ks[r][c4 + 3] = kv.w;
      float4 vv = *(const float4*)(qkv + rowbase + 1536 + (size_t)(kc * 32 + r) * 2304 + c4);
      Vs[r][c4 + 0] = vv.x; Vs[r][c4 + 1] = vv.y; Vs[r][c4 + 2] = vv.z; Vs[r][c4 + 3] = vv.w;
    }
    __syncthreads();  // K/V ready; previous-iter Ps/tmaxs consumers done
    float s[8];
    #pragma unroll
    for (int kk = 0; kk < 8; ++kk) s[kk] = 0.0f;
    for (int d = 0; d < 64; ++d) {
      float qd = Qs[ql][d];
      #pragma unroll
      for (int kk = 0; kk < 8; ++kk) s[kk] += qd * Ks[quad * 8 + kk][d];
    }
    float mloc = NEGINF;
    #pragma unroll
    for (int kk = 0; kk < 8; ++kk) {
      int kg = kc * 32 + quad * 8 + kk;
      if (mask[b * TS + kg] == 0) s[kk] = -3.4028235e38f;
      mloc = fmaxf(mloc, s[kk]);
    }
    float mold = mrow[ql], lold = lrow[ql];
    tmaxs[ql][quad] = mloc;
    __syncthreads();
    float mnew = fmaxf(mold, fmaxf(fmaxf(tmaxs[ql][0], tmaxs[ql][1]),
                                   fmaxf(tmaxs[ql][2], tmaxs[ql][3])));
    float psum = 0.0f;
    #pragma unroll
    for (int kk = 0; kk < 8; ++kk) {
      float p = expf(s[kk] - mnew);
      Ps[ql][quad * 8 + kk] = p;
      psum += p;
    }
    tsums[ql][quad] = psum;
    __syncthreads();
    float alpha = expf(mold - mnew);
    float lnew = lold * alpha + tsums[ql][0] + tsums[ql][1] + tsums[ql][2] + tsums[ql][3];
    if (quad == 0) { mrow[ql] = mnew; lrow[ql] = lnew; }
    #pragma unroll
    for (int di = 0; di < 16; ++di) accv[di] *= alpha;
    #pragma unroll 4
    for (int k = 0; k < 32; ++k) {
      float p = Ps[ql][k];
      #pragma unroll
      for (int di = 0; di < 16; ++di) accv[di] += p * Vs[k][quad * 16 + di];
    }
    __syncthreads();
  }
  float linv = 1.0f / lrow[ql];
  float* o = ctx + (size_t)(b * TS + qt * 64 + ql) * TD + h * 64 + quad * 16;
  #pragma unroll
  for (int di = 0; di < 16; ++di) o[di] = accv[di] * linv;
}

// ---------------- LN2 + gate (fp32 exact path) + x2 bf16 emit ----------------
__global__ __launch_bounds__(256) void ln2_gate_k(const float* __restrict__ attn,
                                                  const float* __restrict__ g,
                                                  const float* __restrict__ bb,
                                                  const float* __restrict__ gw,
                                                  const float* __restrict__ gb,
                                                  __bf16* __restrict__ x2,
                                                  float* __restrict__ gates) {
  __shared__ float red4[4];
  __shared__ float redc[4][7];
  int row = blockIdx.x, tid = threadIdx.x;
  const float* x = attn + (size_t)row * TD;
  float v0 = x[tid], v1 = x[tid + 256], v2 = x[tid + 512];
  float sum = block_sum256(v0 + v1 + v2, red4);
  float mean = sum * (1.0f / 768.0f);
  float d0 = v0 - mean, d1 = v1 - mean, d2 = v2 - mean;
  float var = block_sum256(d0*d0 + d1*d1 + d2*d2, red4) * (1.0f / 768.0f);
  float rs = rsqrtf(var + 1e-12f);
  float xn0 = g[tid]       * (d0 * rs) + bb[tid];
  float xn1 = g[tid + 256] * (d1 * rs) + bb[tid + 256];
  float xn2 = g[tid + 512] * (d2 * rs) + bb[tid + 512];
  __bf16* xo = x2 + (size_t)row * TD;
  xo[tid] = (__bf16)xn0; xo[tid + 256] = (__bf16)xn1; xo[tid + 512] = (__bf16)xn2;
  // gate logit partials (fp32, from fp32 normalized values)
  float p[7];
  #pragma unroll
  for (int e = 0; e < 7; ++e) p[e] = 0.0f;
  const float* w0 = gw + (size_t)tid * 7;
  const float* w1p = gw + (size_t)(tid + 256) * 7;
  const float* w2p = gw + (size_t)(tid + 512) * 7;
  #pragma unroll
  for (int e = 0; e < 7; ++e) p[e] = xn0 * w0[e] + xn1 * w1p[e] + xn2 * w2p[e];
  #pragma unroll
  for (int e = 0; e < 7; ++e)
    #pragma unroll
    for (int o = 32; o > 0; o >>= 1) p[e] += __shfl_down(p[e], o, 64);
  int lane = tid & 63, wv = tid >> 6;
  if (lane == 0) {
    #pragma unroll
    for (int e = 0; e < 7; ++e) redc[wv][e] = p[e];
  }
  __syncthreads();
  if (tid == 0) {
    float l[7];
    #pragma unroll
    for (int e = 0; e < 7; ++e)
      l[e] = redc[0][e] + redc[1][e] + redc[2][e] + redc[3][e] + gb[e];
    int i1 = 0;
    for (int e = 1; e < 7; ++e) if (l[e] > l[i1]) i1 = e;        // ties -> lower idx
    int i2 = -1;
    for (int e = 0; e < 7; ++e) if (e != i1 && (i2 < 0 || l[e] > l[i2])) i2 = e;
    float m = l[i1];
    float e1 = expf(l[i1] - m), e2 = expf(l[i2] - m);
    float inv = 1.0f / (e1 + e2);
    float* go = gates + (size_t)row * 7;
    #pragma unroll
    for (int e = 0; e < 7; ++e) go[e] = 0.0f;
    go[i1] = e1 * inv; go[i2] = e2 * inv;
  }
}

// ---------------- transpose + cast fp32 -> bf16 : out[c][r] = in[r][c] ----------------
__global__ void transpose_cast_k(const float* __restrict__ in, __bf16* __restrict__ out,
                                 int R, int C) {
  __shared__ float tile[32][33];
  size_t zoff = (size_t)blockIdx.z * R * C;
  const float* ip = in + zoff;
  __bf16* op = out + zoff;
  int c0 = blockIdx.x * 32, r0 = blockIdx.y * 32;
  int tx = threadIdx.x, ty = threadIdx.y;  // 32, 8
  #pragma unroll
  for (int i = 0; i < 32; i += 8)
    tile[ty + i][tx] = ip[(size_t)(r0 + ty + i) * C + c0 + tx];
  __syncthreads();
  #pragma unroll
  for (int i = 0; i < 32; i += 8)
    op[(size_t)(c0 + ty + i) * R + r0 + tx] = (__bf16)tile[tx][ty + i];
}

// ---------------- bf16 MFMA GEMM (A [M][K] row-major, BT [N][K] row-major) ----------------
// EPI==0: mid = gelu(acc + bias)  (bf16 out, ldc)
// EPI==1: d_out[t][col] += gates[t][e] * (acc + bias)
template<int EPI>
__global__ __launch_bounds__(256) void gemm_bt_bf16(
    const __bf16* __restrict__ A,
    const __bf16* __restrict__ BT,
    const float* __restrict__ bias,
    const float* __restrict__ gates, int eIdx, int m_base,
    __bf16* __restrict__ Cbf, float* __restrict__ Cacc,
    int Kdim, int ldc)
{
  __shared__ __align__(16) __bf16 As[128][40];
  __shared__ __align__(16) __bf16 Bs[128][40];
  int n0 = blockIdx.x * 128, m0 = blockIdx.y * 128;
  int tid = threadIdx.x;
  int wave = tid >> 6, lane = tid & 63;
  int wr = wave >> 1, wc = wave & 1;
  int lm = lane & 15, q = lane >> 4;
  f32x4_t acc[4][4];
  #pragma unroll
  for (int i = 0; i < 4; ++i)
    #pragma unroll
    for (int j = 0; j < 4; ++j) { f32x4_t z = {0.f, 0.f, 0.f, 0.f}; acc[i][j] = z; }
  for (int k0 = 0; k0 < Kdim; k0 += 32) {
    #pragma unroll
    for (int it = 0; it < 2; ++it) {
      int f = it * 256 + tid; int r = f >> 2; int cg = (f & 3) * 8;
      *(uint4*)(&As[r][cg]) = *(const uint4*)(A + (size_t)(m0 + r) * Kdim + k0 + cg);
      *(uint4*)(&Bs[r][cg]) = *(const uint4*)(BT + (size_t)(n0 + r) * Kdim + k0 + cg);
    }
    __syncthreads();
    bf16x8_t af[4], bfr[4];
    #pragma unroll
    for (int i = 0; i < 4; ++i) af[i]  = *(const bf16x8_t*)(&As[wr * 64 + i * 16 + lm][q * 8]);
    #pragma unroll
    for (int j = 0; j < 4; ++j) bfr[j] = *(const bf16x8_t*)(&Bs[wc * 64 + j * 16 + lm][q * 8]);
    #pragma unroll
    for (int i = 0; i < 4; ++i)
      #pragma unroll
      for (int j = 0; j < 4; ++j)
        acc[i][j] = __builtin_amdgcn_mfma_f32_16x16x32_bf16(af[i], bfr[j], acc[i][j], 0, 0, 0);
    __syncthreads();
  }
  #pragma unroll
  for (int i = 0; i < 4; ++i) {
    #pragma unroll
    for (int j = 0; j < 4; ++j) {
      #pragma unroll
      for (int r = 0; r < 4; ++r) {
        int row = m0 + wr * 64 + i * 16 + q * 4 + r;   // C/D: row=(lane>>4)*4+reg
        int col = n0 + wc * 64 + j * 16 + lm;          //      col=lane&15
        float v = acc[i][j][r] + bias[col];
        if (EPI == 0) {
          v = 0.5f * v * (1.0f + erff(v * 0.70710678118654752f));
          Cbf[(size_t)row * ldc + col] = (__bf16)v;
        } else {
          float gwt = gates[(size_t)(m_base + row) * 7 + eIdx];
          size_t o = (size_t)(m_base + row) * 768 + col;
          Cacc[o] += gwt * v;
        }
      }
    }
  }
}

// ---------------- host launcher ----------------
extern "C" void kernel_launch(void* const* d_in, const int* in_sizes, int n_in,
                              void* d_out, int out_size, void* d_ws, size_t ws_size,
                              hipStream_t stream) {
  (void)in_sizes; (void)n_in; (void)out_size;
  const float* hidden = (const float*)d_in[0];
  const int*   mask   = (const int*)d_in[1];
  const float* ln1_g  = (const float*)d_in[2];
  const float* ln1_b  = (const float*)d_in[3];
  const float* wq = (const float*)d_in[4];  const float* bq = (const float*)d_in[5];
  const float* wk = (const float*)d_in[6];  const float* bk = (const float*)d_in[7];
  const float* wv = (const float*)d_in[8];  const float* bv = (const float*)d_in[9];
  const float* wo = (const float*)d_in[10]; const float* bo = (const float*)d_in[11];
  const float* gate_w = (const float*)d_in[12];
  const float* gate_b = (const float*)d_in[13];
  const float* w1 = (const float*)d_in[14];
  const float* b1 = (const float*)d_in[15];
  const float* w2 = (const float*)d_in[16];
  const float* b2 = (const float*)d_in[17];
  const float* ln2_g = (const float*)d_in[18];
  const float* ln2_b = (const float*)d_in[19];

  float* outp  = (float*)d_out;                       // [8192][768]
  float* gates = (float*)d_out + (size_t)TT * TD;     // [8192][7]

  char* ws = (char*)d_ws;
  float*  x1  = (float*)ws;                              // 25165824 B (also ctx)
  float*  qkv = (float*)(ws + 25165824);                 // 75497472 B
  __bf16* x2  = (__bf16*)(ws + 100663296);               // 12582912 B
  __bf16* w1T = (__bf16*)(ws + 113246208);               // 33030144 B
  __bf16* w2T = (__bf16*)(ws + 146276352);               // 33030144 B
  __bf16* mid = (__bf16*)(ws + 179306496);
  size_t midcap = (ws_size > (size_t)179306496) ? (ws_size - (size_t)179306496) : 0;
  int mid_rows = (int)(midcap / ((size_t)TH * 2));
  mid_rows = (mid_rows / 128) * 128;
  if (mid_rows > TT) mid_rows = TT;
  if (mid_rows < 128) mid_rows = 128;  // requires ws >= ~180 MB

  // 1) LN1
  ln1_k<<<TT, 256, 0, stream>>>(hidden, ln1_g, ln1_b, x1);
  // 2) fused QKV GEMM (fp32) -> qkv [T][2304], q pre-scaled by 1/8
  gemm_f32k<0><<<dim3(18, 64), 256, 0, stream>>>(x1, TD, wq, wk, wv, bq, bk, bv,
                                                 nullptr, qkv, 2304, TD);
  // 3) attention (fp32 flash) -> ctx in x1
  attn_k<<<dim3(8, TNH, TB), 256, 0, stream>>>(qkv, mask, x1);
  // 4) O-proj + bias + residual -> d_out (fp32)
  gemm_f32k<1><<<dim3(6, 64), 256, 0, stream>>>(x1, TD, wo, nullptr, nullptr,
                                                bo, nullptr, nullptr, hidden,
                                                outp, TD, TD);
  // 5) LN2 + gate (fp32 exact) ; emit x2 bf16 and gate_weights
  ln2_gate_k<<<TT, 256, 0, stream>>>(outp, ln2_g, ln2_b, gate_w, gate_b, x2, gates);
  // 6) weight transposes to bf16 B^T layout
  transpose_cast_k<<<dim3(TH / 32, TD / 32, TE), dim3(32, 8), 0, stream>>>(w1, w1T, TD, TH);
  transpose_cast_k<<<dim3(TD / 32, TH / 32, TE), dim3(32, 8), 0, stream>>>(w2, w2T, TH, TD);
  // 7) dense MoE FFN (bf16 MFMA), accumulate weighted experts into d_out
  for (int e = 0; e < TE; ++e) {
    const __bf16* w1Te = w1T + (size_t)e * TH * TD;
    const __bf16* w2Te = w2T + (size_t)e * TD * TH;
    const float*  b1e  = b1 + (size_t)e * TH;
    const float*  b2e  = b2 + (size_t)e * TD;
    for (int c0 = 0; c0 < TT; c0 += mid_rows) {
      int rows = TT - c0; if (rows > mid_rows) rows = mid_rows;
      gemm_bt_bf16<0><<<dim3(TH / 128, rows / 128), 256, 0, stream>>>(
          x2 + (size_t)c0 * TD, w1Te, b1e, nullptr, 0, 0, mid, nullptr, TD, TH);
      gemm_bt_bf16<1><<<dim3(TD / 128, rows / 128), 256, 0, stream>>>(
          mid, w2Te, b2e, gates, e, c0, nullptr, outp, TH, TD);
    }
  }
}

// Round 2
// 1568.467 us; speedup vs baseline: 1.5668x; 1.5668x over previous
//
#include <hip/hip_runtime.h>
#include <hip/hip_bf16.h>
#include <math.h>

#define TB 16
#define TS 512
#define TD 768
#define TH 3072
#define TNH 12
#define TE 7
#define TT (TB*TS)  // 8192 tokens

typedef __bf16 bf16x8_t __attribute__((ext_vector_type(8)));
typedef float f32x4_t __attribute__((ext_vector_type(4)));

#define NEGINF (-__builtin_huge_valf())

// ---- workspace layout (bytes) ----
#define O_X1   0ULL               // x1 (fp32 25.2MB) -> ctx -> x2 (bf16)
#define O_APL  25165824ULL        // A split planes (3x bf16, 37.75MB) -> xg (26.5MB)
#define O_QKV  62914560ULL        // qkv fp32 (75.5MB) -> w1T+w2T (66.1MB)
#define O_BT   138412032ULL       // B^T split planes (QKV: 10.6MB; later O: 3.5MB)
#define O_META 149028864ULL       // meta (<1MB)
#define O_MIDG 150077440ULL       // midg chunks (rest of ws)
// meta sub-offsets (in bytes from O_META)
#define M_CNT   0
#define M_FILL  64
#define M_NRB   192
#define M_RB2E  256
#define M_TOKE  1024
#define M_TOKW  66560
#define M_RTOK  132096
#define M_RGW   201216

#define NRB_MAX 135     // sum ceil(cnt_e/128) <= 128 + 7
#define ROWCAP  17280   // NRB_MAX*128

// ---------------- async global->LDS 16B ----------------
__device__ __forceinline__ void async16(const void* g, void* l) {
  __builtin_amdgcn_global_load_lds(
      (const __attribute__((address_space(1))) void*)g,
      (__attribute__((address_space(3))) void*)l, 16, 0, 0);
}

// ---------------- 3-way exact bf16 split ----------------
__device__ __forceinline__ void split3(float x, __bf16& h, __bf16& m, __bf16& l) {
  h = (__bf16)x;
  float r1 = x - (float)h;
  m = (__bf16)r1;
  float r2 = r1 - (float)m;
  l = (__bf16)r2;
}

// ---------------- block reduction helper (256 threads, 4 waves) ----------------
__device__ __forceinline__ float block_sum256(float v, float* red4) {
  #pragma unroll
  for (int o = 32; o > 0; o >>= 1) v += __shfl_down(v, o, 64);
  int lane = threadIdx.x & 63, wv = threadIdx.x >> 6;
  if (lane == 0) red4[wv] = v;
  __syncthreads();
  float r = red4[0] + red4[1] + red4[2] + red4[3];
  __syncthreads();
  return r;
}

// ---------------- init: zero expert counters ----------------
__global__ void init_meta_k(int* cnt) {
  if (threadIdx.x < TE) cnt[threadIdx.x] = 0;
}

// ---------------- LN1: hidden -> x1 (fp32) ----------------
__global__ __launch_bounds__(256) void ln1_k(const float* __restrict__ in,
                                             const float* __restrict__ g,
                                             const float* __restrict__ bb,
                                             float* __restrict__ out) {
  __shared__ float red4[4];
  int row = blockIdx.x, tid = threadIdx.x;
  const float* x = in + (size_t)row * TD;
  float v0 = x[tid], v1 = x[tid + 256], v2 = x[tid + 512];
  float sum = block_sum256(v0 + v1 + v2, red4);
  float mean = sum * (1.0f / 768.0f);
  float d0 = v0 - mean, d1 = v1 - mean, d2 = v2 - mean;
  float var = block_sum256(d0*d0 + d1*d1 + d2*d2, red4) * (1.0f / 768.0f);
  float rs = rsqrtf(var + 1e-12f);
  float* o = out + (size_t)row * TD;
  o[tid]       = g[tid]       * (d0 * rs) + bb[tid];
  o[tid + 256] = g[tid + 256] * (d1 * rs) + bb[tid + 256];
  o[tid + 512] = g[tid + 512] * (d2 * rs) + bb[tid + 512];
}

// ---------------- split rows fp32 [M][768] -> 3 bf16 planes ----------------
__global__ __launch_bounds__(256) void split3_rows_k(const float* __restrict__ X,
                                                     __bf16* __restrict__ P) {
  const size_t SA = (size_t)TT * TD;
  int row = blockIdx.x, tid = threadIdx.x;
  #pragma unroll
  for (int c = tid; c < TD; c += 256) {
    float x = X[(size_t)row * TD + c];
    __bf16 h, m, l; split3(x, h, m, l);
    size_t o = (size_t)row * TD + c;
    P[o] = h; P[SA + o] = m; P[2*SA + o] = l;
  }
}

// ---------------- transpose + 3-way split: W[768][768] -> BT planes [N][768] ----------------
__global__ void tpose_split3_k(const float* __restrict__ W0, const float* __restrict__ W1,
                               const float* __restrict__ W2,
                               __bf16* __restrict__ BT, size_t SB, int roffmul) {
  __shared__ float tile[32][33];
  const float* W = (blockIdx.z == 0) ? W0 : (blockIdx.z == 1) ? W1 : W2;
  int roff = roffmul * (int)blockIdx.z * TD;
  int c0 = blockIdx.x * 32, r0 = blockIdx.y * 32;
  int tx = threadIdx.x, ty = threadIdx.y;  // 32 x 8
  #pragma unroll
  for (int i = 0; i < 32; i += 8)
    tile[ty + i][tx] = W[(size_t)(r0 + ty + i) * TD + c0 + tx];
  __syncthreads();
  #pragma unroll
  for (int i = 0; i < 32; i += 8) {
    float x = tile[tx][ty + i];   // = W[r0+tx][c0+ty+i]
    __bf16 h, m, l; split3(x, h, m, l);
    size_t o = (size_t)(roff + c0 + ty + i) * TD + r0 + tx;
    BT[o] = h; BT[SB + o] = m; BT[2*SB + o] = l;
  }
}

// ---------------- split-bf16 6-pass GEMM (exact-fp32-grade) ----------------
// A planes [3][8192][768], BT planes [3][N][768].  EPI 0: QKV (+bias, q*0.125) -> C[ldc=2304]
// EPI 1: O-proj + bias + residual -> C[ldc=768]
template<int EPI>
__global__ __launch_bounds__(256) void gemm_split6_k(
    const __bf16* __restrict__ Apl, const __bf16* __restrict__ Bpl, size_t SB,
    const float* __restrict__ bi0, const float* __restrict__ bi1, const float* __restrict__ bi2,
    const float* __restrict__ resid, float* __restrict__ C, int ldc)
{
  __shared__ __align__(16) __bf16 As[3][4096];  // [128][32] each
  __shared__ __align__(16) __bf16 Bs[3][4096];
  const size_t SA = (size_t)TT * TD;
  int n0 = blockIdx.x * 128, m0 = blockIdx.y * 128;
  int tid = threadIdx.x;
  int wave = tid >> 6, lane = tid & 63;
  int wr = wave >> 1, wc = wave & 1;
  int lm = lane & 15, q = lane >> 4;
  f32x4_t acc[4][4];
  #pragma unroll
  for (int i = 0; i < 4; ++i)
    #pragma unroll
    for (int j = 0; j < 4; ++j) { f32x4_t z = {0.f,0.f,0.f,0.f}; acc[i][j] = z; }
  for (int k0 = 0; k0 < TD; k0 += 32) {
    #pragma unroll
    for (int it = 0; it < 2; ++it) {
      int f = it * 256 + tid; int r = f >> 2; int c8 = (f & 3) * 8;
      #pragma unroll
      for (int p = 0; p < 3; ++p) {
        async16(Apl + p * SA + (size_t)(m0 + r) * TD + k0 + c8, &As[p][f * 8]);
        async16(Bpl + p * SB + (size_t)(n0 + r) * TD + k0 + c8, &Bs[p][f * 8]);
      }
    }
    __syncthreads();
    #pragma unroll
    for (int pa = 0; pa < 3; ++pa) {
      bf16x8_t af[4];
      #pragma unroll
      for (int i = 0; i < 4; ++i)
        af[i] = *(const bf16x8_t*)(&As[pa][(wr*64 + i*16 + lm) * 32 + q*8]);
      #pragma unroll
      for (int pb = 0; pb < 3 - pa; ++pb) {
        bf16x8_t bfr[4];
        #pragma unroll
        for (int j = 0; j < 4; ++j)
          bfr[j] = *(const bf16x8_t*)(&Bs[pb][(wc*64 + j*16 + lm) * 32 + q*8]);
        #pragma unroll
        for (int i = 0; i < 4; ++i)
          #pragma unroll
          for (int j = 0; j < 4; ++j)
            acc[i][j] = __builtin_amdgcn_mfma_f32_16x16x32_bf16(af[i], bfr[j], acc[i][j], 0, 0, 0);
      }
    }
    __syncthreads();
  }
  #pragma unroll
  for (int i = 0; i < 4; ++i) {
    #pragma unroll
    for (int j = 0; j < 4; ++j) {
      #pragma unroll
      for (int r = 0; r < 4; ++r) {
        int row = m0 + wr*64 + i*16 + q*4 + r;
        int col = n0 + wc*64 + j*16 + lm;
        float v = acc[i][j][r];
        if (EPI == 0) {
          float bias = (col < 768) ? bi0[col] : (col < 1536) ? bi1[col - 768] : bi2[col - 1536];
          v += bias;
          if (col < 768) v *= 0.125f;
          C[(size_t)row * ldc + col] = v;
        } else {
          v += bi0[col] + resid[(size_t)row * TD + col];
          C[(size_t)row * ldc + col] = v;
        }
      }
    }
  }
}

// ---------------- fp32 flash attention (unchanged) ----------------
__global__ __launch_bounds__(256) void attn_k(const float* __restrict__ qkv,
                                              const int* __restrict__ mask,
                                              float* __restrict__ ctx) {
  __shared__ float Qs[64][65];
  __shared__ float Ks[32][65];
  __shared__ float Vs[32][65];
  __shared__ float Ps[64][33];
  __shared__ float tmaxs[64][4];
  __shared__ float tsums[64][4];
  __shared__ float mrow[64], lrow[64];
  int qt = blockIdx.x, h = blockIdx.y, b = blockIdx.z;
  int tid = threadIdx.x;
  int ql = tid & 63, quad = tid >> 6;
  const size_t rowbase = (size_t)(b * TS) * 2304 + h * 64;
  for (int f = tid; f < 64 * 16; f += 256) {
    int r = f >> 4, c4 = (f & 15) * 4;
    float4 v = *(const float4*)(qkv + rowbase + (size_t)(qt * 64 + r) * 2304 + c4);
    Qs[r][c4 + 0] = v.x; Qs[r][c4 + 1] = v.y; Qs[r][c4 + 2] = v.z; Qs[r][c4 + 3] = v.w;
  }
  if (tid < 64) { mrow[tid] = NEGINF; lrow[tid] = 0.0f; }
  float accv[16];
  #pragma unroll
  for (int i = 0; i < 16; ++i) accv[i] = 0.0f;
  __syncthreads();
  for (int kc = 0; kc < 16; ++kc) {
    for (int f = tid; f < 32 * 16; f += 256) {
      int r = f >> 4, c4 = (f & 15) * 4;
      float4 kv = *(const float4*)(qkv + rowbase + 768 + (size_t)(kc * 32 + r) * 2304 + c4);
      Ks[r][c4 + 0] = kv.x; Ks[r][c4 + 1] = kv.y; Ks[r][c4 + 2] = kv.z; Ks[r][c4 + 3] = kv.w;
      float4 vv = *(const float4*)(qkv + rowbase + 1536 + (size_t)(kc * 32 + r) * 2304 + c4);
      Vs[r][c4 + 0] = vv.x; Vs[r][c4 + 1] = vv.y; Vs[r][c4 + 2] = vv.z; Vs[r][c4 + 3] = vv.w;
    }
    __syncthreads();
    float s[8];
    #pragma unroll
    for (int kk = 0; kk < 8; ++kk) s[kk] = 0.0f;
    for (int d = 0; d < 64; ++d) {
      float qd = Qs[ql][d];
      #pragma unroll
      for (int kk = 0; kk < 8; ++kk) s[kk] += qd * Ks[quad * 8 + kk][d];
    }
    float mloc = NEGINF;
    #pragma unroll
    for (int kk = 0; kk < 8; ++kk) {
      int kg = kc * 32 + quad * 8 + kk;
      if (mask[b * TS + kg] == 0) s[kk] = -3.4028235e38f;
      mloc = fmaxf(mloc, s[kk]);
    }
    float mold = mrow[ql], lold = lrow[ql];
    tmaxs[ql][quad] = mloc;
    __syncthreads();
    float mnew = fmaxf(mold, fmaxf(fmaxf(tmaxs[ql][0], tmaxs[ql][1]),
                                   fmaxf(tmaxs[ql][2], tmaxs[ql][3])));
    float psum = 0.0f;
    #pragma unroll
    for (int kk = 0; kk < 8; ++kk) {
      float p = expf(s[kk] - mnew);
      Ps[ql][quad * 8 + kk] = p;
      psum += p;
    }
    tsums[ql][quad] = psum;
    __syncthreads();
    float alpha = expf(mold - mnew);
    float lnew = lold * alpha + tsums[ql][0] + tsums[ql][1] + tsums[ql][2] + tsums[ql][3];
    if (quad == 0) { mrow[ql] = mnew; lrow[ql] = lnew; }
    #pragma unroll
    for (int di = 0; di < 16; ++di) accv[di] *= alpha;
    #pragma unroll 4
    for (int k = 0; k < 32; ++k) {
      float p = Ps[ql][k];
      #pragma unroll
      for (int di = 0; di < 16; ++di) accv[di] += p * Vs[k][quad * 16 + di];
    }
    __syncthreads();
  }
  float linv = 1.0f / lrow[ql];
  float* o = ctx + (size_t)(b * TS + qt * 64 + ql) * TD + h * 64 + quad * 16;
  #pragma unroll
  for (int di = 0; di < 16; ++di) o[di] = accv[di] * linv;
}

// ---------------- LN2 + gate + routing meta + x2 bf16 ----------------
__global__ __launch_bounds__(256) void ln2_gate_k(const float* __restrict__ attn,
                                                  const float* __restrict__ g,
                                                  const float* __restrict__ bb,
                                                  const float* __restrict__ gw,
                                                  const float* __restrict__ gb,
                                                  __bf16* __restrict__ x2,
                                                  float* __restrict__ gates,
                                                  int* __restrict__ cnt,
                                                  int* __restrict__ tok_e,
                                                  float* __restrict__ tok_w) {
  __shared__ float red4[4];
  __shared__ float redc[4][7];
  int row = blockIdx.x, tid = threadIdx.x;
  const float* x = attn + (size_t)row * TD;
  float v0 = x[tid], v1 = x[tid + 256], v2 = x[tid + 512];
  float sum = block_sum256(v0 + v1 + v2, red4);
  float mean = sum * (1.0f / 768.0f);
  float d0 = v0 - mean, d1 = v1 - mean, d2 = v2 - mean;
  float var = block_sum256(d0*d0 + d1*d1 + d2*d2, red4) * (1.0f / 768.0f);
  float rs = rsqrtf(var + 1e-12f);
  float xn0 = g[tid]       * (d0 * rs) + bb[tid];
  float xn1 = g[tid + 256] * (d1 * rs) + bb[tid + 256];
  float xn2 = g[tid + 512] * (d2 * rs) + bb[tid + 512];
  __bf16* xo = x2 + (size_t)row * TD;
  xo[tid] = (__bf16)xn0; xo[tid + 256] = (__bf16)xn1; xo[tid + 512] = (__bf16)xn2;
  float p[7];
  const float* w0 = gw + (size_t)tid * 7;
  const float* w1p = gw + (size_t)(tid + 256) * 7;
  const float* w2p = gw + (size_t)(tid + 512) * 7;
  #pragma unroll
  for (int e = 0; e < 7; ++e) p[e] = xn0 * w0[e] + xn1 * w1p[e] + xn2 * w2p[e];
  #pragma unroll
  for (int e = 0; e < 7; ++e)
    #pragma unroll
    for (int o = 32; o > 0; o >>= 1) p[e] += __shfl_down(p[e], o, 64);
  int lane = tid & 63, wv = tid >> 6;
  if (lane == 0) {
    #pragma unroll
    for (int e = 0; e < 7; ++e) redc[wv][e] = p[e];
  }
  __syncthreads();
  if (tid == 0) {
    float l[7];
    #pragma unroll
    for (int e = 0; e < 7; ++e)
      l[e] = redc[0][e] + redc[1][e] + redc[2][e] + redc[3][e] + gb[e];
    int i1 = 0;
    for (int e = 1; e < 7; ++e) if (l[e] > l[i1]) i1 = e;
    int i2 = -1;
    for (int e = 0; e < 7; ++e) if (e != i1 && (i2 < 0 || l[e] > l[i2])) i2 = e;
    float m = l[i1];
    float e1 = expf(l[i1] - m), e2 = expf(l[i2] - m);
    float inv = 1.0f / (e1 + e2);
    float g1 = e1 * inv, g2 = e2 * inv;
    float* go = gates + (size_t)row * 7;
    #pragma unroll
    for (int e = 0; e < 7; ++e) go[e] = 0.0f;
    go[i1] = g1; go[i2] = g2;
    tok_e[row * 2] = i1; tok_e[row * 2 + 1] = i2;
    tok_w[row * 2] = g1; tok_w[row * 2 + 1] = g2;
    atomicAdd(&cnt[i1], 1);
    atomicAdd(&cnt[i2], 1);
  }
}

// ---------------- prefix: offsets, rb2e, fill, row_token init ----------------
__global__ void prefix_k(const int* __restrict__ cnt, int* __restrict__ fill,
                         int* __restrict__ nrb_p, int* __restrict__ rb2e,
                         int* __restrict__ row_token) {
  int tid = threadIdx.x;
  if (tid == 0) {
    int acc = 0;
    for (int e = 0; e < TE; ++e) {
      int nb = (cnt[e] + 127) >> 7;
      fill[e] = acc * 128;
      for (int b = 0; b < nb; ++b) rb2e[acc + b] = e;
      acc += nb;
    }
    nrb_p[0] = acc;
  }
  for (int i = tid; i < ROWCAP; i += 256) row_token[i] = -1;
}

// ---------------- scatter: x2 rows -> xg (gathered, per-expert contiguous) ----------------
__global__ __launch_bounds__(256) void scatter_k(const __bf16* __restrict__ x2,
                                                 const int* __restrict__ tok_e,
                                                 const float* __restrict__ tok_w,
                                                 int* __restrict__ fill,
                                                 __bf16* __restrict__ xg,
                                                 int* __restrict__ row_token,
                                                 float* __restrict__ row_gw) {
  int t = blockIdx.x, tid = threadIdx.x;
  __shared__ int slots[2];
  if (tid < 2) {
    int e = tok_e[t * 2 + tid];
    slots[tid] = atomicAdd(&fill[e], 1);
  }
  __syncthreads();
  if (tid < 192) {
    int j = tid / 96, c = tid - j * 96;
    int s = slots[j];
    *(uint4*)(xg + (size_t)s * TD + c * 8) =
        *(const uint4*)(x2 + (size_t)t * TD + c * 8);
    if (c == 0) { row_token[s] = t; row_gw[s] = tok_w[t * 2 + j]; }
  }
}

// ---------------- transpose + cast fp32 -> bf16 : out[c][r] = in[r][c] ----------------
__global__ void transpose_cast_k(const float* __restrict__ in, __bf16* __restrict__ out,
                                 int R, int C) {
  __shared__ float tile[32][33];
  size_t zoff = (size_t)blockIdx.z * R * C;
  const float* ip = in + zoff;
  __bf16* op = out + zoff;
  int c0 = blockIdx.x * 32, r0 = blockIdx.y * 32;
  int tx = threadIdx.x, ty = threadIdx.y;  // 32, 8
  #pragma unroll
  for (int i = 0; i < 32; i += 8)
    tile[ty + i][tx] = ip[(size_t)(r0 + ty + i) * C + c0 + tx];
  __syncthreads();
  #pragma unroll
  for (int i = 0; i < 32; i += 8)
    op[(size_t)(c0 + ty + i) * R + r0 + tx] = (__bf16)tile[tx][ty + i];
}

// ---------------- sparse FFN GEMM1: mid = gelu(xg @ w1[e] + b1[e]) ----------------
__global__ __launch_bounds__(256) void gemm1_k(
    const __bf16* __restrict__ xg, const __bf16* __restrict__ w1T,
    const float* __restrict__ b1, const int* __restrict__ rb2e,
    const int* __restrict__ nrb_p, int cb, __bf16* __restrict__ midg)
{
  int rb = cb + blockIdx.y;
  if (rb >= nrb_p[0]) return;
  int e = rb2e[rb];
  __shared__ __align__(16) __bf16 As[4096];
  __shared__ __align__(16) __bf16 Bs[4096];
  const __bf16* A = xg + (size_t)rb * 128 * TD;
  const __bf16* BT = w1T + (size_t)e * TH * TD;
  const float* be = b1 + (size_t)e * TH;
  int n0 = blockIdx.x * 128;
  int tid = threadIdx.x;
  int wave = tid >> 6, lane = tid & 63;
  int wr = wave >> 1, wc = wave & 1;
  int lm = lane & 15, q = lane >> 4;
  f32x4_t acc[4][4];
  #pragma unroll
  for (int i = 0; i < 4; ++i)
    #pragma unroll
    for (int j = 0; j < 4; ++j) { f32x4_t z = {0.f,0.f,0.f,0.f}; acc[i][j] = z; }
  for (int k0 = 0; k0 < TD; k0 += 32) {
    #pragma unroll
    for (int it = 0; it < 2; ++it) {
      int f = it * 256 + tid; int r = f >> 2; int c8 = (f & 3) * 8;
      async16(A + (size_t)r * TD + k0 + c8, &As[f * 8]);
      async16(BT + (size_t)(n0 + r) * TD + k0 + c8, &Bs[f * 8]);
    }
    __syncthreads();
    bf16x8_t af[4], bfr[4];
    #pragma unroll
    for (int i = 0; i < 4; ++i) af[i]  = *(const bf16x8_t*)(&As[(wr*64 + i*16 + lm)*32 + q*8]);
    #pragma unroll
    for (int j = 0; j < 4; ++j) bfr[j] = *(const bf16x8_t*)(&Bs[(wc*64 + j*16 + lm)*32 + q*8]);
    #pragma unroll
    for (int i = 0; i < 4; ++i)
      #pragma unroll
      for (int j = 0; j < 4; ++j)
        acc[i][j] = __builtin_amdgcn_mfma_f32_16x16x32_bf16(af[i], bfr[j], acc[i][j], 0, 0, 0);
    __syncthreads();
  }
  #pragma unroll
  for (int i = 0; i < 4; ++i) {
    #pragma unroll
    for (int j = 0; j < 4; ++j) {
      #pragma unroll
      for (int r = 0; r < 4; ++r) {
        int row = wr*64 + i*16 + q*4 + r;
        int col = n0 + wc*64 + j*16 + lm;
        float v = acc[i][j][r] + be[col];
        v = 0.5f * v * (1.0f + erff(v * 0.70710678118654752f));
        midg[(size_t)(blockIdx.y * 128 + row) * TH + col] = (__bf16)v;
      }
    }
  }
}

// ---------------- sparse FFN GEMM2: out[tok] += gw * (mid @ w2[e] + b2[e]) ----------------
__global__ __launch_bounds__(256) void gemm2_k(
    const __bf16* __restrict__ midg, const __bf16* __restrict__ w2T,
    const float* __restrict__ b2, const int* __restrict__ rb2e,
    const int* __restrict__ nrb_p, const int* __restrict__ row_token,
    const float* __restrict__ row_gw, int cb, float* __restrict__ outp)
{
  int rb = cb + blockIdx.y;
  if (rb >= nrb_p[0]) return;
  int e = rb2e[rb];
  __shared__ __align__(16) __bf16 As[4096];
  __shared__ __align__(16) __bf16 Bs[4096];
  const __bf16* A = midg + (size_t)blockIdx.y * 128 * TH;
  const __bf16* BT = w2T + (size_t)e * TD * TH;
  const float* be = b2 + (size_t)e * TD;
  int n0 = blockIdx.x * 128;
  int kbase = blockIdx.z * (TH / 2);
  int tid = threadIdx.x;
  int wave = tid >> 6, lane = tid & 63;
  int wr = wave >> 1, wc = wave & 1;
  int lm = lane & 15, q = lane >> 4;
  f32x4_t acc[4][4];
  #pragma unroll
  for (int i = 0; i < 4; ++i)
    #pragma unroll
    for (int j = 0; j < 4; ++j) { f32x4_t z = {0.f,0.f,0.f,0.f}; acc[i][j] = z; }
  for (int k0 = kbase; k0 < kbase + TH / 2; k0 += 32) {
    #pragma unroll
    for (int it = 0; it < 2; ++it) {
      int f = it * 256 + tid; int r = f >> 2; int c8 = (f & 3) * 8;
      async16(A + (size_t)r * TH + k0 + c8, &As[f * 8]);
      async16(BT + (size_t)(n0 + r) * TH + k0 + c8, &Bs[f * 8]);
    }
    __syncthreads();
    bf16x8_t af[4], bfr[4];
    #pragma unroll
    for (int i = 0; i < 4; ++i) af[i]  = *(const bf16x8_t*)(&As[(wr*64 + i*16 + lm)*32 + q*8]);
    #pragma unroll
    for (int j = 0; j < 4; ++j) bfr[j] = *(const bf16x8_t*)(&Bs[(wc*64 + j*16 + lm)*32 + q*8]);
    #pragma unroll
    for (int i = 0; i < 4; ++i)
      #pragma unroll
      for (int j = 0; j < 4; ++j)
        acc[i][j] = __builtin_amdgcn_mfma_f32_16x16x32_bf16(af[i], bfr[j], acc[i][j], 0, 0, 0);
    __syncthreads();
  }
  #pragma unroll
  for (int i = 0; i < 4; ++i) {
    #pragma unroll
    for (int r = 0; r < 4; ++r) {
      int row = wr*64 + i*16 + q*4 + r;
      int grow = rb * 128 + row;
      int t = row_token[grow];
      if (t < 0) continue;
      float gwt = row_gw[grow];
      #pragma unroll
      for (int j = 0; j < 4; ++j) {
        int col = n0 + wc*64 + j*16 + lm;
        float v = acc[i][j][r];
        if (blockIdx.z == 0) v += be[col];
        atomicAdd(&outp[(size_t)t * TD + col], gwt * v);
      }
    }
  }
}

// ---------------- host launcher ----------------
extern "C" void kernel_launch(void* const* d_in, const int* in_sizes, int n_in,
                              void* d_out, int out_size, void* d_ws, size_t ws_size,
                              hipStream_t stream) {
  (void)in_sizes; (void)n_in; (void)out_size;
  const float* hidden = (const float*)d_in[0];
  const int*   mask   = (const int*)d_in[1];
  const float* ln1_g  = (const float*)d_in[2];
  const float* ln1_b  = (const float*)d_in[3];
  const float* wq = (const float*)d_in[4];  const float* bq = (const float*)d_in[5];
  const float* wk = (const float*)d_in[6];  const float* bk = (const float*)d_in[7];
  const float* wv = (const float*)d_in[8];  const float* bv = (const float*)d_in[9];
  const float* wo = (const float*)d_in[10]; const float* bo = (const float*)d_in[11];
  const float* gate_w = (const float*)d_in[12];
  const float* gate_b = (const float*)d_in[13];
  const float* w1 = (const float*)d_in[14];
  const float* b1 = (const float*)d_in[15];
  const float* w2 = (const float*)d_in[16];
  const float* b2 = (const float*)d_in[17];
  const float* ln2_g = (const float*)d_in[18];
  const float* ln2_b = (const float*)d_in[19];

  float* outp  = (float*)d_out;                       // [8192][768]
  float* gates = (float*)d_out + (size_t)TT * TD;     // [8192][7]

  char* ws = (char*)d_ws;
  float*  x1   = (float*)(ws + O_X1);
  __bf16* x2   = (__bf16*)(ws + O_X1);
  __bf16* Apl  = (__bf16*)(ws + O_APL);
  __bf16* xg   = (__bf16*)(ws + O_APL);
  float*  qkv  = (float*)(ws + O_QKV);
  __bf16* w1T  = (__bf16*)(ws + O_QKV);
  __bf16* w2T  = (__bf16*)(ws + O_QKV + (size_t)TE * TH * TD * 2);
  __bf16* BTq  = (__bf16*)(ws + O_BT);
  __bf16* BTo  = (__bf16*)(ws + O_BT);
  char*   meta = ws + O_META;
  int*   cnt      = (int*)(meta + M_CNT);
  int*   fill     = (int*)(meta + M_FILL);
  int*   nrb_p    = (int*)(meta + M_NRB);
  int*   rb2e     = (int*)(meta + M_RB2E);
  int*   tok_e    = (int*)(meta + M_TOKE);
  float* tok_w    = (float*)(meta + M_TOKW);
  int*   row_token= (int*)(meta + M_RTOK);
  float* row_gw   = (float*)(meta + M_RGW);
  __bf16* midg = (__bf16*)(ws + O_MIDG);

  // chunk capacity (rowblocks of 128 tokens) from remaining workspace
  long long midcap = (long long)ws_size - (long long)O_MIDG;
  int crb = (int)(midcap / (128LL * TH * 2));
  if (crb < 1) crb = 1;
  if (crb > NRB_MAX) crb = NRB_MAX;

  // 0) zero expert counters
  init_meta_k<<<1, 64, 0, stream>>>(cnt);
  // 1) LN1 -> x1
  ln1_k<<<TT, 256, 0, stream>>>(hidden, ln1_g, ln1_b, x1);
  // 2) split x1 -> A planes; transpose+split wq|wk|wv -> BTq planes [2304][768]
  split3_rows_k<<<TT, 256, 0, stream>>>(x1, Apl);
  tpose_split3_k<<<dim3(24, 24, 3), dim3(32, 8), 0, stream>>>(
      wq, wk, wv, BTq, (size_t)2304 * TD, 1);
  // 3) QKV via 6-pass split GEMM -> qkv (q pre-scaled 0.125)
  gemm_split6_k<0><<<dim3(18, 64), 256, 0, stream>>>(
      Apl, BTq, (size_t)2304 * TD, bq, bk, bv, nullptr, qkv, 2304);
  // 4) attention -> ctx (x1 region)
  attn_k<<<dim3(8, TNH, TB), 256, 0, stream>>>(qkv, mask, x1);
  // 5) split ctx -> A planes; transpose+split wo -> BTo [768][768]
  split3_rows_k<<<TT, 256, 0, stream>>>(x1, Apl);
  tpose_split3_k<<<dim3(24, 24, 1), dim3(32, 8), 0, stream>>>(
      wo, wo, wo, BTo, (size_t)TD * TD, 0);
  // 6) O-proj + bias + residual -> outp (d_out)
  gemm_split6_k<1><<<dim3(6, 64), 256, 0, stream>>>(
      Apl, BTo, (size_t)TD * TD, bo, nullptr, nullptr, hidden, outp, TD);
  // 7) LN2 + gate + routing meta; x2 bf16 (x1 region)
  ln2_gate_k<<<TT, 256, 0, stream>>>(outp, ln2_g, ln2_b, gate_w, gate_b, x2, gates,
                                     cnt, tok_e, tok_w);
  // 8) prefix + row_token init
  prefix_k<<<1, 256, 0, stream>>>(cnt, fill, nrb_p, rb2e, row_token);
  // 9) scatter x2 rows -> xg (Apl region)
  scatter_k<<<TT, 256, 0, stream>>>(x2, tok_e, tok_w, fill, xg, row_token, row_gw);
  // 10) expert weights -> bf16 B^T layout (qkv region)
  transpose_cast_k<<<dim3(TH / 32, TD / 32, TE), dim3(32, 8), 0, stream>>>(w1, w1T, TD, TH);
  transpose_cast_k<<<dim3(TD / 32, TH / 32, TE), dim3(32, 8), 0, stream>>>(w2, w2T, TH, TD);
  // 11) sparse FFN over rowblock chunks
  for (int cb = 0; cb < NRB_MAX; cb += crb) {
    int nb = NRB_MAX - cb; if (nb > crb) nb = crb;
    gemm1_k<<<dim3(TH / 128, nb), 256, 0, stream>>>(xg, w1T, b1, rb2e, nrb_p, cb, midg);
    gemm2_k<<<dim3(TD / 128, nb, 2), 256, 0, stream>>>(midg, w2T, b2, rb2e, nrb_p,
                                                       row_token, row_gw, cb, outp);
  }
}

// Round 3
// 1305.018 us; speedup vs baseline: 1.8831x; 1.2019x over previous
//
#include <hip/hip_runtime.h>
#include <hip/hip_bf16.h>
#include <math.h>

#define TB 16
#define TS 512
#define TD 768
#define TH 3072
#define TNH 12
#define TE 7
#define TT (TB*TS)  // 8192 tokens

typedef __bf16 bf16x8_t __attribute__((ext_vector_type(8)));
typedef float f32x4_t __attribute__((ext_vector_type(4)));

#define NEGINF (-__builtin_huge_valf())

// ---- workspace layout (bytes) ----
// Phase A: Apl(0..37.7M) + BTq(138.4M) -> qkh/qkm/vcol
// Phase B: vT kernel: vcol -> vT planes @0 (Apl dead)
// Attn: reads qkh/qkm/vT -> ctx planes (37.7M gap + vcol region)
// O-proj: ctx planes + BTo -> d_out
// FFN: x2@62.9M, xg@75.5M, w1T@0, w2T@33M, midg@150M
#define O_APL   0ULL
#define O_VT0   0ULL
#define O_VT1   12582912ULL
#define O_VT2   25165824ULL
#define O_CTXH  37748736ULL
#define O_CTXM  50331648ULL
#define O_QKH   62914560ULL
#define O_QKM   88080384ULL
#define O_VCOL  113246208ULL
#define O_CTXL  113246208ULL
#define O_BT    138412032ULL
#define O_META  149028864ULL
#define O_MIDG  150077440ULL
#define O_X2    62914560ULL
#define O_XG    75497472ULL
#define O_W1T   0ULL
#define O_W2T   33030144ULL
// meta sub-offsets
#define M_CNT   0
#define M_FILL  64
#define M_NRB   192
#define M_RB2E  256
#define M_TOKE  1024
#define M_TOKW  66560
#define M_RTOK  132096
#define M_RGW   201216

#define NRB_MAX 135
#define ROWCAP  17280

// ---------------- async global->LDS 16B ----------------
__device__ __forceinline__ void async16(const void* g, void* l) {
  __builtin_amdgcn_global_load_lds(
      (const __attribute__((address_space(1))) void*)g,
      (__attribute__((address_space(3))) void*)l, 16, 0, 0);
}

// ---------------- 3-way exact bf16 split ----------------
__device__ __forceinline__ void split3(float x, __bf16& h, __bf16& m, __bf16& l) {
  h = (__bf16)x;
  float r1 = x - (float)h;
  m = (__bf16)r1;
  float r2 = r1 - (float)m;
  l = (__bf16)r2;
}

// ---------------- block reduction helper ----------------
__device__ __forceinline__ float block_sum256(float v, float* red4) {
  #pragma unroll
  for (int o = 32; o > 0; o >>= 1) v += __shfl_down(v, o, 64);
  int lane = threadIdx.x & 63, wv = threadIdx.x >> 6;
  if (lane == 0) red4[wv] = v;
  __syncthreads();
  float r = red4[0] + red4[1] + red4[2] + red4[3];
  __syncthreads();
  return r;
}

__global__ void init_meta_k(int* cnt) {
  if (threadIdx.x < TE) cnt[threadIdx.x] = 0;
}

// ---------------- LN1 fused with split3: hidden -> Apl planes ----------------
__global__ __launch_bounds__(256) void ln1_split_k(const float* __restrict__ in,
                                                   const float* __restrict__ g,
                                                   const float* __restrict__ bb,
                                                   __bf16* __restrict__ P) {
  __shared__ float red4[4];
  const size_t SA = (size_t)TT * TD;
  int row = blockIdx.x, tid = threadIdx.x;
  const float* x = in + (size_t)row * TD;
  float v0 = x[tid], v1 = x[tid + 256], v2 = x[tid + 512];
  float sum = block_sum256(v0 + v1 + v2, red4);
  float mean = sum * (1.0f / 768.0f);
  float d0 = v0 - mean, d1 = v1 - mean, d2 = v2 - mean;
  float var = block_sum256(d0*d0 + d1*d1 + d2*d2, red4) * (1.0f / 768.0f);
  float rs = rsqrtf(var + 1e-12f);
  float xn[3] = { g[tid]       * (d0 * rs) + bb[tid],
                  g[tid + 256] * (d1 * rs) + bb[tid + 256],
                  g[tid + 512] * (d2 * rs) + bb[tid + 512] };
  #pragma unroll
  for (int i = 0; i < 3; ++i) {
    __bf16 h, m, l; split3(xn[i], h, m, l);
    size_t o = (size_t)row * TD + tid + 256 * i;
    P[o] = h; P[SA + o] = m; P[2*SA + o] = l;
  }
}

// ---------------- transpose + 3-way split weights ----------------
__global__ void tpose_split3_k(const float* __restrict__ W0, const float* __restrict__ W1,
                               const float* __restrict__ W2,
                               __bf16* __restrict__ BT, size_t SB, int roffmul) {
  __shared__ float tile[32][33];
  const float* W = (blockIdx.z == 0) ? W0 : (blockIdx.z == 1) ? W1 : W2;
  int roff = roffmul * (int)blockIdx.z * TD;
  int c0 = blockIdx.x * 32, r0 = blockIdx.y * 32;
  int tx = threadIdx.x, ty = threadIdx.y;
  #pragma unroll
  for (int i = 0; i < 32; i += 8)
    tile[ty + i][tx] = W[(size_t)(r0 + ty + i) * TD + c0 + tx];
  __syncthreads();
  #pragma unroll
  for (int i = 0; i < 32; i += 8) {
    float x = tile[tx][ty + i];
    __bf16 h, m, l; split3(x, h, m, l);
    size_t o = (size_t)(roff + c0 + ty + i) * TD + r0 + tx;
    BT[o] = h; BT[SB + o] = m; BT[2*SB + o] = l;
  }
}

// ---------------- split-bf16 6-pass GEMM ----------------
// EPI 0: QKV -> Q/K bf16 split-2 planes [T][1536] + V fp32 [T][768]
// EPI 1: O-proj + bias + residual -> C fp32 [T][768]
template<int EPI>
__global__ __launch_bounds__(256) void gemm_split6_k(
    const __bf16* __restrict__ A0, const __bf16* __restrict__ A1, const __bf16* __restrict__ A2,
    const __bf16* __restrict__ Bpl, size_t SB,
    const float* __restrict__ bi0, const float* __restrict__ bi1, const float* __restrict__ bi2,
    const float* __restrict__ resid, float* __restrict__ C,
    __bf16* __restrict__ qh_out, __bf16* __restrict__ qm_out, float* __restrict__ vout)
{
  __shared__ __align__(16) __bf16 As[3][4096];
  __shared__ __align__(16) __bf16 Bs[3][4096];
  const __bf16* Ap[3] = {A0, A1, A2};
  int n0 = blockIdx.x * 128, m0 = blockIdx.y * 128;
  int tid = threadIdx.x;
  int wave = tid >> 6, lane = tid & 63;
  int wr = wave >> 1, wc = wave & 1;
  int lm = lane & 15, q = lane >> 4;
  f32x4_t acc[4][4];
  #pragma unroll
  for (int i = 0; i < 4; ++i)
    #pragma unroll
    for (int j = 0; j < 4; ++j) { f32x4_t z = {0.f,0.f,0.f,0.f}; acc[i][j] = z; }
  for (int k0 = 0; k0 < TD; k0 += 32) {
    #pragma unroll
    for (int it = 0; it < 2; ++it) {
      int f = it * 256 + tid; int r = f >> 2; int c8 = (f & 3) * 8;
      #pragma unroll
      for (int p = 0; p < 3; ++p) {
        async16(Ap[p] + (size_t)(m0 + r) * TD + k0 + c8, &As[p][f * 8]);
        async16(Bpl + p * SB + (size_t)(n0 + r) * TD + k0 + c8, &Bs[p][f * 8]);
      }
    }
    __syncthreads();
    #pragma unroll
    for (int pa = 0; pa < 3; ++pa) {
      bf16x8_t af[4];
      #pragma unroll
      for (int i = 0; i < 4; ++i)
        af[i] = *(const bf16x8_t*)(&As[pa][(wr*64 + i*16 + lm) * 32 + q*8]);
      #pragma unroll
      for (int pb = 0; pb < 3 - pa; ++pb) {
        bf16x8_t bfr[4];
        #pragma unroll
        for (int j = 0; j < 4; ++j)
          bfr[j] = *(const bf16x8_t*)(&Bs[pb][(wc*64 + j*16 + lm) * 32 + q*8]);
        #pragma unroll
        for (int i = 0; i < 4; ++i)
          #pragma unroll
          for (int j = 0; j < 4; ++j)
            acc[i][j] = __builtin_amdgcn_mfma_f32_16x16x32_bf16(af[i], bfr[j], acc[i][j], 0, 0, 0);
      }
    }
    __syncthreads();
  }
  #pragma unroll
  for (int i = 0; i < 4; ++i) {
    #pragma unroll
    for (int j = 0; j < 4; ++j) {
      #pragma unroll
      for (int r = 0; r < 4; ++r) {
        int row = m0 + wr*64 + i*16 + q*4 + r;
        int col = n0 + wc*64 + j*16 + lm;
        float v = acc[i][j][r];
        if (EPI == 0) {
          float bias = (col < 768) ? bi0[col] : (col < 1536) ? bi1[col - 768] : bi2[col - 1536];
          v += bias;
          if (col < 768) v *= 0.125f;
          if (col < 1536) {
            __bf16 hh = (__bf16)v; float r1 = v - (float)hh;
            qh_out[(size_t)row * 1536 + col] = hh;
            qm_out[(size_t)row * 1536 + col] = (__bf16)r1;
          } else {
            vout[(size_t)row * TD + (col - 1536)] = v;
          }
        } else {
          v += bi0[col] + resid[(size_t)row * TD + col];
          C[(size_t)row * TD + col] = v;
        }
      }
    }
  }
}

// ---------------- V transpose + split3: vcol [T][768] -> vT [192][64][512] x3 ----------------
__global__ void vT_split3_k(const float* __restrict__ vcol,
                            __bf16* __restrict__ v0, __bf16* __restrict__ v1,
                            __bf16* __restrict__ v2) {
  __shared__ float tile[32][33];
  int s0 = blockIdx.x * 32, d0 = blockIdx.y * 32, bh = blockIdx.z;
  int b = bh / 12, h = bh - b * 12;
  int tx = threadIdx.x, ty = threadIdx.y;  // 32 x 8
  #pragma unroll
  for (int i = 0; i < 32; i += 8)
    tile[ty + i][tx] = vcol[(size_t)(b * TS + s0 + ty + i) * TD + h * 64 + d0 + tx];
  __syncthreads();
  #pragma unroll
  for (int i = 0; i < 32; i += 8) {
    float x = tile[tx][ty + i];   // = V[s0+tx][d0+ty+i]
    __bf16 hh, mm, ll; split3(x, hh, mm, ll);
    size_t o = (size_t)(bh * 64 + d0 + ty + i) * TS + s0 + tx;
    v0[o] = hh; v1[o] = mm; v2[o] = ll;
  }
}

// ---------------- MFMA flash attention ----------------
// grid (8 qtiles of 64, 12 heads, 16 batch), 256 thr (4 waves, 16 q-rows each).
// Q/K split-2 (3-pass QK), P/V split-3 (6-pass PV). Output: ctx split-3 planes.
#define AST 72
__global__ __launch_bounds__(256) void attn_mfma_k(
    const __bf16* __restrict__ qkh, const __bf16* __restrict__ qkm,
    const __bf16* __restrict__ vT0, const __bf16* __restrict__ vT1,
    const __bf16* __restrict__ vT2, const int* __restrict__ mask,
    __bf16* __restrict__ ch, __bf16* __restrict__ cm, __bf16* __restrict__ cl)
{
  __shared__ __align__(16) __bf16 KS[2][64 * AST];
  __shared__ __align__(16) __bf16 VS[3][64 * AST];
  __shared__ __align__(16) __bf16 PS[3][64 * AST];
  __shared__ float maskadd[512];
  int qt = blockIdx.x, h = blockIdx.y, b = blockIdx.z;
  int tid = threadIdx.x, w = tid >> 6, lane = tid & 63;
  int lm = lane & 15, quad = lane >> 4;
  int t0 = b * TS, t0q = t0 + qt * 64, bh = b * TNH + h;
  for (int i = tid; i < 512; i += 256)
    maskadd[i] = (mask[t0 + i] != 0) ? 0.0f : -1e30f;
  // stage Q planes into PS[0]/PS[1], read A-frags to regs
  #pragma unroll
  for (int it = 0; it < 2; ++it) {
    int f = it * 256 + tid, r = f >> 3, c8 = (f & 7) * 8;
    *(uint4*)&PS[0][r * AST + c8] = *(const uint4*)(qkh + (size_t)(t0q + r) * 1536 + h * 64 + c8);
    *(uint4*)&PS[1][r * AST + c8] = *(const uint4*)(qkm + (size_t)(t0q + r) * 1536 + h * 64 + c8);
  }
  __syncthreads();
  bf16x8_t qf[2][2];
  #pragma unroll
  for (int p = 0; p < 2; ++p)
    #pragma unroll
    for (int ks = 0; ks < 2; ++ks)
      qf[p][ks] = *(const bf16x8_t*)&PS[p][(w * 16 + lm) * AST + ks * 32 + quad * 8];
  __syncthreads();
  f32x4_t Oacc[4];
  #pragma unroll
  for (int j = 0; j < 4; ++j) { f32x4_t z = {0.f,0.f,0.f,0.f}; Oacc[j] = z; }
  float mst[4], lst[4];
  #pragma unroll
  for (int r = 0; r < 4; ++r) { mst[r] = -3.0e38f; lst[r] = 0.0f; }

  for (int kc = 0; kc < 8; ++kc) {
    // ---- stage K (2 planes) + V^T (3 planes) ----
    #pragma unroll
    for (int it = 0; it < 2; ++it) {
      int f = it * 256 + tid, r = f >> 3, c8 = (f & 7) * 8;
      size_t ksrc = (size_t)(t0 + kc * 64 + r) * 1536 + 768 + h * 64 + c8;
      *(uint4*)&KS[0][r * AST + c8] = *(const uint4*)(qkh + ksrc);
      *(uint4*)&KS[1][r * AST + c8] = *(const uint4*)(qkm + ksrc);
      size_t vsrc = (size_t)(bh * 64 + r) * TS + kc * 64 + c8;
      *(uint4*)&VS[0][r * AST + c8] = *(const uint4*)(vT0 + vsrc);
      *(uint4*)&VS[1][r * AST + c8] = *(const uint4*)(vT1 + vsrc);
      *(uint4*)&VS[2][r * AST + c8] = *(const uint4*)(vT2 + vsrc);
    }
    __syncthreads();
    // ---- QK^T: 3 passes (qh*kh, qh*km, qm*kh) ----
    f32x4_t sacc[4];
    #pragma unroll
    for (int j = 0; j < 4; ++j) { f32x4_t z = {0.f,0.f,0.f,0.f}; sacc[j] = z; }
    #pragma unroll
    for (int ks = 0; ks < 2; ++ks) {
      bf16x8_t kh_[4], km_[4];
      #pragma unroll
      for (int jn = 0; jn < 4; ++jn) {
        kh_[jn] = *(const bf16x8_t*)&KS[0][(jn*16 + lm) * AST + ks*32 + quad*8];
        km_[jn] = *(const bf16x8_t*)&KS[1][(jn*16 + lm) * AST + ks*32 + quad*8];
      }
      #pragma unroll
      for (int jn = 0; jn < 4; ++jn)
        sacc[jn] = __builtin_amdgcn_mfma_f32_16x16x32_bf16(qf[0][ks], kh_[jn], sacc[jn], 0,0,0);
      #pragma unroll
      for (int jn = 0; jn < 4; ++jn)
        sacc[jn] = __builtin_amdgcn_mfma_f32_16x16x32_bf16(qf[0][ks], km_[jn], sacc[jn], 0,0,0);
      #pragma unroll
      for (int jn = 0; jn < 4; ++jn)
        sacc[jn] = __builtin_amdgcn_mfma_f32_16x16x32_bf16(qf[1][ks], kh_[jn], sacc[jn], 0,0,0);
    }
    // ---- online softmax (registers; rows = quad*4+r) ----
    float s[4][4];
    #pragma unroll
    for (int jn = 0; jn < 4; ++jn)
      #pragma unroll
      for (int r = 0; r < 4; ++r)
        s[jn][r] = sacc[jn][r] + maskadd[kc*64 + jn*16 + lm];
    float alpha[4];
    #pragma unroll
    for (int r = 0; r < 4; ++r) {
      float rmax = fmaxf(fmaxf(s[0][r], s[1][r]), fmaxf(s[2][r], s[3][r]));
      #pragma unroll
      for (int mk = 1; mk < 16; mk <<= 1)
        rmax = fmaxf(rmax, __shfl_xor(rmax, mk, 64));
      float mnew = fmaxf(mst[r], rmax);
      alpha[r] = expf(mst[r] - mnew);
      mst[r] = mnew;
      float psum = 0.0f;
      #pragma unroll
      for (int jn = 0; jn < 4; ++jn) {
        float p = expf(s[jn][r] - mnew);
        s[jn][r] = p;
        psum += p;
      }
      #pragma unroll
      for (int mk = 1; mk < 16; mk <<= 1)
        psum += __shfl_xor(psum, mk, 64);
      lst[r] = lst[r] * alpha[r] + psum;
    }
    #pragma unroll
    for (int jn = 0; jn < 4; ++jn)
      #pragma unroll
      for (int r = 0; r < 4; ++r)
        Oacc[jn][r] *= alpha[r];
    // ---- P split-3 -> LDS ----
    #pragma unroll
    for (int jn = 0; jn < 4; ++jn)
      #pragma unroll
      for (int r = 0; r < 4; ++r) {
        __bf16 ph, pm, pl; split3(s[jn][r], ph, pm, pl);
        int pa = (w*16 + quad*4 + r) * AST + jn*16 + lm;
        PS[0][pa] = ph; PS[1][pa] = pm; PS[2][pa] = pl;
      }
    __syncthreads();
    // ---- PV: 6 passes lower-triangle (pa+pb<3) ----
    #pragma unroll
    for (int ks = 0; ks < 2; ++ks) {
      bf16x8_t af[3];
      #pragma unroll
      for (int p = 0; p < 3; ++p)
        af[p] = *(const bf16x8_t*)&PS[p][(w*16 + lm) * AST + ks*32 + quad*8];
      bf16x8_t vf[3][4];
      #pragma unroll
      for (int p = 0; p < 3; ++p)
        #pragma unroll
        for (int jn = 0; jn < 4; ++jn)
          vf[p][jn] = *(const bf16x8_t*)&VS[p][(jn*16 + lm) * AST + ks*32 + quad*8];
      #pragma unroll
      for (int jn = 0; jn < 4; ++jn) {
        Oacc[jn] = __builtin_amdgcn_mfma_f32_16x16x32_bf16(af[0], vf[0][jn], Oacc[jn], 0,0,0);
        Oacc[jn] = __builtin_amdgcn_mfma_f32_16x16x32_bf16(af[0], vf[1][jn], Oacc[jn], 0,0,0);
        Oacc[jn] = __builtin_amdgcn_mfma_f32_16x16x32_bf16(af[0], vf[2][jn], Oacc[jn], 0,0,0);
        Oacc[jn] = __builtin_amdgcn_mfma_f32_16x16x32_bf16(af[1], vf[0][jn], Oacc[jn], 0,0,0);
        Oacc[jn] = __builtin_amdgcn_mfma_f32_16x16x32_bf16(af[1], vf[1][jn], Oacc[jn], 0,0,0);
        Oacc[jn] = __builtin_amdgcn_mfma_f32_16x16x32_bf16(af[2], vf[0][jn], Oacc[jn], 0,0,0);
      }
    }
    __syncthreads();
  }
  // ---- epilogue: O/l -> ctx split-3 planes ----
  float linv[4];
  #pragma unroll
  for (int r = 0; r < 4; ++r) linv[r] = 1.0f / lst[r];
  #pragma unroll
  for (int jn = 0; jn < 4; ++jn)
    #pragma unroll
    for (int r = 0; r < 4; ++r) {
      float o = Oacc[jn][r] * linv[r];
      __bf16 hh, mm, ll; split3(o, hh, mm, ll);
      size_t oo = (size_t)(t0q + w*16 + quad*4 + r) * TD + h*64 + jn*16 + lm;
      ch[oo] = hh; cm[oo] = mm; cl[oo] = ll;
    }
}

// ---------------- LN2 + gate + routing meta + x2 bf16 ----------------
__global__ __launch_bounds__(256) void ln2_gate_k(const float* __restrict__ attn,
                                                  const float* __restrict__ g,
                                                  const float* __restrict__ bb,
                                                  const float* __restrict__ gw,
                                                  const float* __restrict__ gb,
                                                  __bf16* __restrict__ x2,
                                                  float* __restrict__ gates,
                                                  int* __restrict__ cnt,
                                                  int* __restrict__ tok_e,
                                                  float* __restrict__ tok_w) {
  __shared__ float red4[4];
  __shared__ float redc[4][7];
  int row = blockIdx.x, tid = threadIdx.x;
  const float* x = attn + (size_t)row * TD;
  float v0 = x[tid], v1 = x[tid + 256], v2 = x[tid + 512];
  float sum = block_sum256(v0 + v1 + v2, red4);
  float mean = sum * (1.0f / 768.0f);
  float d0 = v0 - mean, d1 = v1 - mean, d2 = v2 - mean;
  float var = block_sum256(d0*d0 + d1*d1 + d2*d2, red4) * (1.0f / 768.0f);
  float rs = rsqrtf(var + 1e-12f);
  float xn0 = g[tid]       * (d0 * rs) + bb[tid];
  float xn1 = g[tid + 256] * (d1 * rs) + bb[tid + 256];
  float xn2 = g[tid + 512] * (d2 * rs) + bb[tid + 512];
  __bf16* xo = x2 + (size_t)row * TD;
  xo[tid] = (__bf16)xn0; xo[tid + 256] = (__bf16)xn1; xo[tid + 512] = (__bf16)xn2;
  float p[7];
  const float* w0 = gw + (size_t)tid * 7;
  const float* w1p = gw + (size_t)(tid + 256) * 7;
  const float* w2p = gw + (size_t)(tid + 512) * 7;
  #pragma unroll
  for (int e = 0; e < 7; ++e) p[e] = xn0 * w0[e] + xn1 * w1p[e] + xn2 * w2p[e];
  #pragma unroll
  for (int e = 0; e < 7; ++e)
    #pragma unroll
    for (int o = 32; o > 0; o >>= 1) p[e] += __shfl_down(p[e], o, 64);
  int lane = tid & 63, wv = tid >> 6;
  if (lane == 0) {
    #pragma unroll
    for (int e = 0; e < 7; ++e) redc[wv][e] = p[e];
  }
  __syncthreads();
  if (tid == 0) {
    float l[7];
    #pragma unroll
    for (int e = 0; e < 7; ++e)
      l[e] = redc[0][e] + redc[1][e] + redc[2][e] + redc[3][e] + gb[e];
    int i1 = 0;
    for (int e = 1; e < 7; ++e) if (l[e] > l[i1]) i1 = e;
    int i2 = -1;
    for (int e = 0; e < 7; ++e) if (e != i1 && (i2 < 0 || l[e] > l[i2])) i2 = e;
    float m = l[i1];
    float e1 = expf(l[i1] - m), e2 = expf(l[i2] - m);
    float inv = 1.0f / (e1 + e2);
    float g1 = e1 * inv, g2 = e2 * inv;
    float* go = gates + (size_t)row * 7;
    #pragma unroll
    for (int e = 0; e < 7; ++e) go[e] = 0.0f;
    go[i1] = g1; go[i2] = g2;
    tok_e[row * 2] = i1; tok_e[row * 2 + 1] = i2;
    tok_w[row * 2] = g1; tok_w[row * 2 + 1] = g2;
    atomicAdd(&cnt[i1], 1);
    atomicAdd(&cnt[i2], 1);
  }
}

// ---------------- prefix ----------------
__global__ void prefix_k(const int* __restrict__ cnt, int* __restrict__ fill,
                         int* __restrict__ nrb_p, int* __restrict__ rb2e,
                         int* __restrict__ row_token) {
  int tid = threadIdx.x;
  if (tid == 0) {
    int acc = 0;
    for (int e = 0; e < TE; ++e) {
      int nb = (cnt[e] + 127) >> 7;
      fill[e] = acc * 128;
      for (int b = 0; b < nb; ++b) rb2e[acc + b] = e;
      acc += nb;
    }
    nrb_p[0] = acc;
  }
  for (int i = tid; i < ROWCAP; i += 256) row_token[i] = -1;
}

// ---------------- scatter ----------------
__global__ __launch_bounds__(256) void scatter_k(const __bf16* __restrict__ x2,
                                                 const int* __restrict__ tok_e,
                                                 const float* __restrict__ tok_w,
                                                 int* __restrict__ fill,
                                                 __bf16* __restrict__ xg,
                                                 int* __restrict__ row_token,
                                                 float* __restrict__ row_gw) {
  int t = blockIdx.x, tid = threadIdx.x;
  __shared__ int slots[2];
  if (tid < 2) {
    int e = tok_e[t * 2 + tid];
    slots[tid] = atomicAdd(&fill[e], 1);
  }
  __syncthreads();
  if (tid < 192) {
    int j = tid / 96, c = tid - j * 96;
    int s = slots[j];
    *(uint4*)(xg + (size_t)s * TD + c * 8) =
        *(const uint4*)(x2 + (size_t)t * TD + c * 8);
    if (c == 0) { row_token[s] = t; row_gw[s] = tok_w[t * 2 + j]; }
  }
}

// ---------------- transpose + cast fp32 -> bf16 ----------------
__global__ void transpose_cast_k(const float* __restrict__ in, __bf16* __restrict__ out,
                                 int R, int C) {
  __shared__ float tile[32][33];
  size_t zoff = (size_t)blockIdx.z * R * C;
  const float* ip = in + zoff;
  __bf16* op = out + zoff;
  int c0 = blockIdx.x * 32, r0 = blockIdx.y * 32;
  int tx = threadIdx.x, ty = threadIdx.y;
  #pragma unroll
  for (int i = 0; i < 32; i += 8)
    tile[ty + i][tx] = ip[(size_t)(r0 + ty + i) * C + c0 + tx];
  __syncthreads();
  #pragma unroll
  for (int i = 0; i < 32; i += 8)
    op[(size_t)(c0 + ty + i) * R + r0 + tx] = (__bf16)tile[tx][ty + i];
}

// ---------------- sparse FFN GEMM1 ----------------
__global__ __launch_bounds__(256) void gemm1_k(
    const __bf16* __restrict__ xg, const __bf16* __restrict__ w1T,
    const float* __restrict__ b1, const int* __restrict__ rb2e,
    const int* __restrict__ nrb_p, int cb, __bf16* __restrict__ midg)
{
  int rb = cb + blockIdx.y;
  if (rb >= nrb_p[0]) return;
  int e = rb2e[rb];
  __shared__ __align__(16) __bf16 As[4096];
  __shared__ __align__(16) __bf16 Bs[4096];
  const __bf16* A = xg + (size_t)rb * 128 * TD;
  const __bf16* BT = w1T + (size_t)e * TH * TD;
  const float* be = b1 + (size_t)e * TH;
  int n0 = blockIdx.x * 128;
  int tid = threadIdx.x;
  int wave = tid >> 6, lane = tid & 63;
  int wr = wave >> 1, wc = wave & 1;
  int lm = lane & 15, q = lane >> 4;
  f32x4_t acc[4][4];
  #pragma unroll
  for (int i = 0; i < 4; ++i)
    #pragma unroll
    for (int j = 0; j < 4; ++j) { f32x4_t z = {0.f,0.f,0.f,0.f}; acc[i][j] = z; }
  for (int k0 = 0; k0 < TD; k0 += 32) {
    #pragma unroll
    for (int it = 0; it < 2; ++it) {
      int f = it * 256 + tid; int r = f >> 2; int c8 = (f & 3) * 8;
      async16(A + (size_t)r * TD + k0 + c8, &As[f * 8]);
      async16(BT + (size_t)(n0 + r) * TD + k0 + c8, &Bs[f * 8]);
    }
    __syncthreads();
    bf16x8_t af[4], bfr[4];
    #pragma unroll
    for (int i = 0; i < 4; ++i) af[i]  = *(const bf16x8_t*)(&As[(wr*64 + i*16 + lm)*32 + q*8]);
    #pragma unroll
    for (int j = 0; j < 4; ++j) bfr[j] = *(const bf16x8_t*)(&Bs[(wc*64 + j*16 + lm)*32 + q*8]);
    #pragma unroll
    for (int i = 0; i < 4; ++i)
      #pragma unroll
      for (int j = 0; j < 4; ++j)
        acc[i][j] = __builtin_amdgcn_mfma_f32_16x16x32_bf16(af[i], bfr[j], acc[i][j], 0, 0, 0);
    __syncthreads();
  }
  #pragma unroll
  for (int i = 0; i < 4; ++i) {
    #pragma unroll
    for (int j = 0; j < 4; ++j) {
      #pragma unroll
      for (int r = 0; r < 4; ++r) {
        int row = wr*64 + i*16 + q*4 + r;
        int col = n0 + wc*64 + j*16 + lm;
        float v = acc[i][j][r] + be[col];
        v = 0.5f * v * (1.0f + erff(v * 0.70710678118654752f));
        midg[(size_t)(blockIdx.y * 128 + row) * TH + col] = (__bf16)v;
      }
    }
  }
}

// ---------------- sparse FFN GEMM2 ----------------
__global__ __launch_bounds__(256) void gemm2_k(
    const __bf16* __restrict__ midg, const __bf16* __restrict__ w2T,
    const float* __restrict__ b2, const int* __restrict__ rb2e,
    const int* __restrict__ nrb_p, const int* __restrict__ row_token,
    const float* __restrict__ row_gw, int cb, float* __restrict__ outp)
{
  int rb = cb + blockIdx.y;
  if (rb >= nrb_p[0]) return;
  int e = rb2e[rb];
  __shared__ __align__(16) __bf16 As[4096];
  __shared__ __align__(16) __bf16 Bs[4096];
  const __bf16* A = midg + (size_t)blockIdx.y * 128 * TH;
  const __bf16* BT = w2T + (size_t)e * TD * TH;
  const float* be = b2 + (size_t)e * TD;
  int n0 = blockIdx.x * 128;
  int kbase = blockIdx.z * (TH / 2);
  int tid = threadIdx.x;
  int wave = tid >> 6, lane = tid & 63;
  int wr = wave >> 1, wc = wave & 1;
  int lm = lane & 15, q = lane >> 4;
  f32x4_t acc[4][4];
  #pragma unroll
  for (int i = 0; i < 4; ++i)
    #pragma unroll
    for (int j = 0; j < 4; ++j) { f32x4_t z = {0.f,0.f,0.f,0.f}; acc[i][j] = z; }
  for (int k0 = kbase; k0 < kbase + TH / 2; k0 += 32) {
    #pragma unroll
    for (int it = 0; it < 2; ++it) {
      int f = it * 256 + tid; int r = f >> 2; int c8 = (f & 3) * 8;
      async16(A + (size_t)r * TH + k0 + c8, &As[f * 8]);
      async16(BT + (size_t)(n0 + r) * TH + k0 + c8, &Bs[f * 8]);
    }
    __syncthreads();
    bf16x8_t af[4], bfr[4];
    #pragma unroll
    for (int i = 0; i < 4; ++i) af[i]  = *(const bf16x8_t*)(&As[(wr*64 + i*16 + lm)*32 + q*8]);
    #pragma unroll
    for (int j = 0; j < 4; ++j) bfr[j] = *(const bf16x8_t*)(&Bs[(wc*64 + j*16 + lm)*32 + q*8]);
    #pragma unroll
    for (int i = 0; i < 4; ++i)
      #pragma unroll
      for (int j = 0; j < 4; ++j)
        acc[i][j] = __builtin_amdgcn_mfma_f32_16x16x32_bf16(af[i], bfr[j], acc[i][j], 0, 0, 0);
    __syncthreads();
  }
  #pragma unroll
  for (int i = 0; i < 4; ++i) {
    #pragma unroll
    for (int r = 0; r < 4; ++r) {
      int row = wr*64 + i*16 + q*4 + r;
      int grow = rb * 128 + row;
      int t = row_token[grow];
      if (t < 0) continue;
      float gwt = row_gw[grow];
      #pragma unroll
      for (int j = 0; j < 4; ++j) {
        int col = n0 + wc*64 + j*16 + lm;
        float v = acc[i][j][r];
        if (blockIdx.z == 0) v += be[col];
        atomicAdd(&outp[(size_t)t * TD + col], gwt * v);
      }
    }
  }
}

// ---------------- host launcher ----------------
extern "C" void kernel_launch(void* const* d_in, const int* in_sizes, int n_in,
                              void* d_out, int out_size, void* d_ws, size_t ws_size,
                              hipStream_t stream) {
  (void)in_sizes; (void)n_in; (void)out_size;
  const float* hidden = (const float*)d_in[0];
  const int*   mask   = (const int*)d_in[1];
  const float* ln1_g  = (const float*)d_in[2];
  const float* ln1_b  = (const float*)d_in[3];
  const float* wq = (const float*)d_in[4];  const float* bq = (const float*)d_in[5];
  const float* wk = (const float*)d_in[6];  const float* bk = (const float*)d_in[7];
  const float* wv = (const float*)d_in[8];  const float* bv = (const float*)d_in[9];
  const float* wo = (const float*)d_in[10]; const float* bo = (const float*)d_in[11];
  const float* gate_w = (const float*)d_in[12];
  const float* gate_b = (const float*)d_in[13];
  const float* w1 = (const float*)d_in[14];
  const float* b1 = (const float*)d_in[15];
  const float* w2 = (const float*)d_in[16];
  const float* b2 = (const float*)d_in[17];
  const float* ln2_g = (const float*)d_in[18];
  const float* ln2_b = (const float*)d_in[19];

  float* outp  = (float*)d_out;
  float* gates = (float*)d_out + (size_t)TT * TD;

  char* ws = (char*)d_ws;
  __bf16* Apl  = (__bf16*)(ws + O_APL);
  __bf16* vT0p = (__bf16*)(ws + O_VT0);
  __bf16* vT1p = (__bf16*)(ws + O_VT1);
  __bf16* vT2p = (__bf16*)(ws + O_VT2);
  __bf16* ctxh = (__bf16*)(ws + O_CTXH);
  __bf16* ctxm = (__bf16*)(ws + O_CTXM);
  __bf16* ctxl = (__bf16*)(ws + O_CTXL);
  __bf16* qkh  = (__bf16*)(ws + O_QKH);
  __bf16* qkm  = (__bf16*)(ws + O_QKM);
  float*  vcol = (float*)(ws + O_VCOL);
  __bf16* BTp  = (__bf16*)(ws + O_BT);
  __bf16* x2   = (__bf16*)(ws + O_X2);
  __bf16* xg   = (__bf16*)(ws + O_XG);
  __bf16* w1T  = (__bf16*)(ws + O_W1T);
  __bf16* w2T  = (__bf16*)(ws + O_W2T);
  char*   meta = ws + O_META;
  int*   cnt      = (int*)(meta + M_CNT);
  int*   fill     = (int*)(meta + M_FILL);
  int*   nrb_p    = (int*)(meta + M_NRB);
  int*   rb2e     = (int*)(meta + M_RB2E);
  int*   tok_e    = (int*)(meta + M_TOKE);
  float* tok_w    = (float*)(meta + M_TOKW);
  int*   row_token= (int*)(meta + M_RTOK);
  float* row_gw   = (float*)(meta + M_RGW);
  __bf16* midg = (__bf16*)(ws + O_MIDG);

  long long midcap = (long long)ws_size - (long long)O_MIDG;
  int crb = (int)(midcap / (128LL * TH * 2));
  if (crb < 1) crb = 1;
  if (crb > NRB_MAX) crb = NRB_MAX;

  const size_t SA = (size_t)TT * TD;

  // 0) meta init
  init_meta_k<<<1, 64, 0, stream>>>(cnt);
  // 1) LN1 + split3 -> Apl
  ln1_split_k<<<TT, 256, 0, stream>>>(hidden, ln1_g, ln1_b, Apl);
  // 2) wq|wk|wv -> BTq split planes [2304][768]
  tpose_split3_k<<<dim3(24, 24, 3), dim3(32, 8), 0, stream>>>(
      wq, wk, wv, BTp, (size_t)2304 * TD, 1);
  // 3) QKV split6 GEMM -> qkh/qkm (split-2, q scaled) + vcol fp32
  gemm_split6_k<0><<<dim3(18, 64), 256, 0, stream>>>(
      Apl, Apl + SA, Apl + 2*SA, BTp, (size_t)2304 * TD,
      bq, bk, bv, nullptr, nullptr, qkh, qkm, vcol);
  // 4) V transpose + split3 -> vT planes (overwrites Apl region)
  vT_split3_k<<<dim3(16, 2, 192), dim3(32, 8), 0, stream>>>(vcol, vT0p, vT1p, vT2p);
  // 5) MFMA flash attention -> ctx split-3 planes
  attn_mfma_k<<<dim3(8, TNH, TB), 256, 0, stream>>>(
      qkh, qkm, vT0p, vT1p, vT2p, mask, ctxh, ctxm, ctxl);
  // 6) wo -> BTo split planes [768][768]
  tpose_split3_k<<<dim3(24, 24, 1), dim3(32, 8), 0, stream>>>(
      wo, wo, wo, BTp, (size_t)TD * TD, 0);
  // 7) O-proj split6 + bias + residual -> outp
  gemm_split6_k<1><<<dim3(6, 64), 256, 0, stream>>>(
      ctxh, ctxm, ctxl, BTp, (size_t)TD * TD,
      bo, nullptr, nullptr, hidden, outp, nullptr, nullptr, nullptr);
  // 8) LN2 + gate + routing
  ln2_gate_k<<<TT, 256, 0, stream>>>(outp, ln2_g, ln2_b, gate_w, gate_b, x2, gates,
                                     cnt, tok_e, tok_w);
  // 9) prefix + scatter
  prefix_k<<<1, 256, 0, stream>>>(cnt, fill, nrb_p, rb2e, row_token);
  scatter_k<<<TT, 256, 0, stream>>>(x2, tok_e, tok_w, fill, xg, row_token, row_gw);
  // 10) expert weights -> bf16 B^T
  transpose_cast_k<<<dim3(TH / 32, TD / 32, TE), dim3(32, 8), 0, stream>>>(w1, w1T, TD, TH);
  transpose_cast_k<<<dim3(TD / 32, TH / 32, TE), dim3(32, 8), 0, stream>>>(w2, w2T, TH, TD);
  // 11) sparse FFN
  for (int cb = 0; cb < NRB_MAX; cb += crb) {
    int nb = NRB_MAX - cb; if (nb > crb) nb = crb;
    gemm1_k<<<dim3(TH / 128, nb), 256, 0, stream>>>(xg, w1T, b1, rb2e, nrb_p, cb, midg);
    gemm2_k<<<dim3(TD / 128, nb, 2), 256, 0, stream>>>(midg, w2T, b2, rb2e, nrb_p,
                                                       row_token, row_gw, cb, outp);
  }
}

// Round 4
// 1250.979 us; speedup vs baseline: 1.9645x; 1.0432x over previous
//
#include <hip/hip_runtime.h>
#include <hip/hip_bf16.h>
#include <math.h>

#define TB 16
#define TS 512
#define TD 768
#define TH 3072
#define TNH 12
#define TE 7
#define TT (TB*TS)  // 8192 tokens

typedef __bf16 bf16x8_t __attribute__((ext_vector_type(8)));
typedef __bf16 bf16x4_t __attribute__((ext_vector_type(4)));
typedef float f32x4_t __attribute__((ext_vector_type(4)));

#define NEGINF (-__builtin_huge_valf())

// ---- workspace layout (bytes) ----
#define O_APL   0ULL
#define O_VT0   0ULL
#define O_VT1   12582912ULL
#define O_VT2   25165824ULL
#define O_CTXH  37748736ULL
#define O_CTXM  50331648ULL
#define O_QKH   62914560ULL
#define O_QKM   88080384ULL
#define O_VCOL  113246208ULL
#define O_CTXL  113246208ULL
#define O_BT    138412032ULL
#define O_META  149028864ULL
#define O_MIDG  150077440ULL
#define O_X2    62914560ULL
#define O_XG    75497472ULL   // xg during gemm1; re-used as part[] during gemm2/gather
#define O_W1T   0ULL
#define O_W2T   33030144ULL
// meta sub-offsets
#define M_CNT   0
#define M_FILL  64
#define M_NRB   192
#define M_RB2E  256
#define M_TOKE  1024
#define M_TOKW  66560
#define M_RGW   201216
#define M_TSLOT 270336

#define NRB_MAX 135
#define ROWCAP  17280

// ---------------- async global->LDS 16B ----------------
__device__ __forceinline__ void async16(const void* g, void* l) {
  __builtin_amdgcn_global_load_lds(
      (const __attribute__((address_space(1))) void*)g,
      (__attribute__((address_space(3))) void*)l, 16, 0, 0);
}

// ---------------- 3-way exact bf16 split ----------------
__device__ __forceinline__ void split3(float x, __bf16& h, __bf16& m, __bf16& l) {
  h = (__bf16)x;
  float r1 = x - (float)h;
  m = (__bf16)r1;
  float r2 = r1 - (float)m;
  l = (__bf16)r2;
}

// ---------------- block reduction helper ----------------
__device__ __forceinline__ float block_sum256(float v, float* red4) {
  #pragma unroll
  for (int o = 32; o > 0; o >>= 1) v += __shfl_down(v, o, 64);
  int lane = threadIdx.x & 63, wv = threadIdx.x >> 6;
  if (lane == 0) red4[wv] = v;
  __syncthreads();
  float r = red4[0] + red4[1] + red4[2] + red4[3];
  __syncthreads();
  return r;
}

__global__ void init_meta_k(int* cnt) {
  if (threadIdx.x < TE) cnt[threadIdx.x] = 0;
}

// ---------------- LN1 fused with split3: hidden -> Apl planes ----------------
__global__ __launch_bounds__(256) void ln1_split_k(const float* __restrict__ in,
                                                   const float* __restrict__ g,
                                                   const float* __restrict__ bb,
                                                   __bf16* __restrict__ P) {
  __shared__ float red4[4];
  const size_t SA = (size_t)TT * TD;
  int row = blockIdx.x, tid = threadIdx.x;
  const float* x = in + (size_t)row * TD;
  float v0 = x[tid], v1 = x[tid + 256], v2 = x[tid + 512];
  float sum = block_sum256(v0 + v1 + v2, red4);
  float mean = sum * (1.0f / 768.0f);
  float d0 = v0 - mean, d1 = v1 - mean, d2 = v2 - mean;
  float var = block_sum256(d0*d0 + d1*d1 + d2*d2, red4) * (1.0f / 768.0f);
  float rs = rsqrtf(var + 1e-12f);
  float xn[3] = { g[tid]       * (d0 * rs) + bb[tid],
                  g[tid + 256] * (d1 * rs) + bb[tid + 256],
                  g[tid + 512] * (d2 * rs) + bb[tid + 512] };
  #pragma unroll
  for (int i = 0; i < 3; ++i) {
    __bf16 h, m, l; split3(xn[i], h, m, l);
    size_t o = (size_t)row * TD + tid + 256 * i;
    P[o] = h; P[SA + o] = m; P[2*SA + o] = l;
  }
}

// ---------------- transpose + 3-way split weights ----------------
__global__ void tpose_split3_k(const float* __restrict__ W0, const float* __restrict__ W1,
                               const float* __restrict__ W2,
                               __bf16* __restrict__ BT, size_t SB, int roffmul) {
  __shared__ float tile[32][33];
  const float* W = (blockIdx.z == 0) ? W0 : (blockIdx.z == 1) ? W1 : W2;
  int roff = roffmul * (int)blockIdx.z * TD;
  int c0 = blockIdx.x * 32, r0 = blockIdx.y * 32;
  int tx = threadIdx.x, ty = threadIdx.y;
  #pragma unroll
  for (int i = 0; i < 32; i += 8)
    tile[ty + i][tx] = W[(size_t)(r0 + ty + i) * TD + c0 + tx];
  __syncthreads();
  #pragma unroll
  for (int i = 0; i < 32; i += 8) {
    float x = tile[tx][ty + i];
    __bf16 h, m, l; split3(x, h, m, l);
    size_t o = (size_t)(roff + c0 + ty + i) * TD + r0 + tx;
    BT[o] = h; BT[SB + o] = m; BT[2*SB + o] = l;
  }
}

// ---------------- split-bf16 6-pass GEMM ----------------
template<int EPI>
__global__ __launch_bounds__(256) void gemm_split6_k(
    const __bf16* __restrict__ A0, const __bf16* __restrict__ A1, const __bf16* __restrict__ A2,
    const __bf16* __restrict__ Bpl, size_t SB,
    const float* __restrict__ bi0, const float* __restrict__ bi1, const float* __restrict__ bi2,
    const float* __restrict__ resid, float* __restrict__ C,
    __bf16* __restrict__ qh_out, __bf16* __restrict__ qm_out, float* __restrict__ vout)
{
  __shared__ __align__(16) __bf16 As[3][4096];
  __shared__ __align__(16) __bf16 Bs[3][4096];
  const __bf16* Ap[3] = {A0, A1, A2};
  int n0 = blockIdx.x * 128, m0 = blockIdx.y * 128;
  int tid = threadIdx.x;
  int wave = tid >> 6, lane = tid & 63;
  int wr = wave >> 1, wc = wave & 1;
  int lm = lane & 15, q = lane >> 4;
  f32x4_t acc[4][4];
  #pragma unroll
  for (int i = 0; i < 4; ++i)
    #pragma unroll
    for (int j = 0; j < 4; ++j) { f32x4_t z = {0.f,0.f,0.f,0.f}; acc[i][j] = z; }
  for (int k0 = 0; k0 < TD; k0 += 32) {
    #pragma unroll
    for (int it = 0; it < 2; ++it) {
      int f = it * 256 + tid; int r = f >> 2; int c8 = (f & 3) * 8;
      #pragma unroll
      for (int p = 0; p < 3; ++p) {
        async16(Ap[p] + (size_t)(m0 + r) * TD + k0 + c8, &As[p][f * 8]);
        async16(Bpl + p * SB + (size_t)(n0 + r) * TD + k0 + c8, &Bs[p][f * 8]);
      }
    }
    __syncthreads();
    #pragma unroll
    for (int pa = 0; pa < 3; ++pa) {
      bf16x8_t af[4];
      #pragma unroll
      for (int i = 0; i < 4; ++i)
        af[i] = *(const bf16x8_t*)(&As[pa][(wr*64 + i*16 + lm) * 32 + q*8]);
      #pragma unroll
      for (int pb = 0; pb < 3 - pa; ++pb) {
        bf16x8_t bfr[4];
        #pragma unroll
        for (int j = 0; j < 4; ++j)
          bfr[j] = *(const bf16x8_t*)(&Bs[pb][(wc*64 + j*16 + lm) * 32 + q*8]);
        #pragma unroll
        for (int i = 0; i < 4; ++i)
          #pragma unroll
          for (int j = 0; j < 4; ++j)
            acc[i][j] = __builtin_amdgcn_mfma_f32_16x16x32_bf16(af[i], bfr[j], acc[i][j], 0, 0, 0);
      }
    }
    __syncthreads();
  }
  #pragma unroll
  for (int i = 0; i < 4; ++i) {
    #pragma unroll
    for (int j = 0; j < 4; ++j) {
      #pragma unroll
      for (int r = 0; r < 4; ++r) {
        int row = m0 + wr*64 + i*16 + q*4 + r;
        int col = n0 + wc*64 + j*16 + lm;
        float v = acc[i][j][r];
        if (EPI == 0) {
          float bias = (col < 768) ? bi0[col] : (col < 1536) ? bi1[col - 768] : bi2[col - 1536];
          v += bias;
          if (col < 768) v *= 0.125f;
          if (col < 1536) {
            __bf16 hh = (__bf16)v; float r1 = v - (float)hh;
            qh_out[(size_t)row * 1536 + col] = hh;
            qm_out[(size_t)row * 1536 + col] = (__bf16)r1;
          } else {
            vout[(size_t)row * TD + (col - 1536)] = v;
          }
        } else {
          v += bi0[col] + resid[(size_t)row * TD + col];
          C[(size_t)row * TD + col] = v;
        }
      }
    }
  }
}

// ---------------- V transpose + split3 ----------------
__global__ void vT_split3_k(const float* __restrict__ vcol,
                            __bf16* __restrict__ v0, __bf16* __restrict__ v1,
                            __bf16* __restrict__ v2) {
  __shared__ float tile[32][33];
  int s0 = blockIdx.x * 32, d0 = blockIdx.y * 32, bh = blockIdx.z;
  int b = bh / 12, h = bh - b * 12;
  int tx = threadIdx.x, ty = threadIdx.y;
  #pragma unroll
  for (int i = 0; i < 32; i += 8)
    tile[ty + i][tx] = vcol[(size_t)(b * TS + s0 + ty + i) * TD + h * 64 + d0 + tx];
  __syncthreads();
  #pragma unroll
  for (int i = 0; i < 32; i += 8) {
    float x = tile[tx][ty + i];
    __bf16 hh, mm, ll; split3(x, hh, mm, ll);
    size_t o = (size_t)(bh * 64 + d0 + ty + i) * TS + s0 + tx;
    v0[o] = hh; v1[o] = mm; v2[o] = ll;
  }
}

// ---------------- MFMA flash attention ----------------
#define AST 72
__global__ __launch_bounds__(256) void attn_mfma_k(
    const __bf16* __restrict__ qkh, const __bf16* __restrict__ qkm,
    const __bf16* __restrict__ vT0, const __bf16* __restrict__ vT1,
    const __bf16* __restrict__ vT2, const int* __restrict__ mask,
    __bf16* __restrict__ ch, __bf16* __restrict__ cm, __bf16* __restrict__ cl)
{
  __shared__ __align__(16) __bf16 KS[2][64 * AST];
  __shared__ __align__(16) __bf16 VS[3][64 * AST];
  __shared__ __align__(16) __bf16 PS[3][64 * AST];
  __shared__ float maskadd[512];
  int qt = blockIdx.x, h = blockIdx.y, b = blockIdx.z;
  int tid = threadIdx.x, w = tid >> 6, lane = tid & 63;
  int lm = lane & 15, quad = lane >> 4;
  int t0 = b * TS, t0q = t0 + qt * 64, bh = b * TNH + h;
  for (int i = tid; i < 512; i += 256)
    maskadd[i] = (mask[t0 + i] != 0) ? 0.0f : -1e30f;
  #pragma unroll
  for (int it = 0; it < 2; ++it) {
    int f = it * 256 + tid, r = f >> 3, c8 = (f & 7) * 8;
    *(uint4*)&PS[0][r * AST + c8] = *(const uint4*)(qkh + (size_t)(t0q + r) * 1536 + h * 64 + c8);
    *(uint4*)&PS[1][r * AST + c8] = *(const uint4*)(qkm + (size_t)(t0q + r) * 1536 + h * 64 + c8);
  }
  __syncthreads();
  bf16x8_t qf[2][2];
  #pragma unroll
  for (int p = 0; p < 2; ++p)
    #pragma unroll
    for (int ks = 0; ks < 2; ++ks)
      qf[p][ks] = *(const bf16x8_t*)&PS[p][(w * 16 + lm) * AST + ks * 32 + quad * 8];
  __syncthreads();
  f32x4_t Oacc[4];
  #pragma unroll
  for (int j = 0; j < 4; ++j) { f32x4_t z = {0.f,0.f,0.f,0.f}; Oacc[j] = z; }
  float mst[4], lst[4];
  #pragma unroll
  for (int r = 0; r < 4; ++r) { mst[r] = -3.0e38f; lst[r] = 0.0f; }

  for (int kc = 0; kc < 8; ++kc) {
    #pragma unroll
    for (int it = 0; it < 2; ++it) {
      int f = it * 256 + tid, r = f >> 3, c8 = (f & 7) * 8;
      size_t ksrc = (size_t)(t0 + kc * 64 + r) * 1536 + 768 + h * 64 + c8;
      *(uint4*)&KS[0][r * AST + c8] = *(const uint4*)(qkh + ksrc);
      *(uint4*)&KS[1][r * AST + c8] = *(const uint4*)(qkm + ksrc);
      size_t vsrc = (size_t)(bh * 64 + r) * TS + kc * 64 + c8;
      *(uint4*)&VS[0][r * AST + c8] = *(const uint4*)(vT0 + vsrc);
      *(uint4*)&VS[1][r * AST + c8] = *(const uint4*)(vT1 + vsrc);
      *(uint4*)&VS[2][r * AST + c8] = *(const uint4*)(vT2 + vsrc);
    }
    __syncthreads();
    f32x4_t sacc[4];
    #pragma unroll
    for (int j = 0; j < 4; ++j) { f32x4_t z = {0.f,0.f,0.f,0.f}; sacc[j] = z; }
    #pragma unroll
    for (int ks = 0; ks < 2; ++ks) {
      bf16x8_t kh_[4], km_[4];
      #pragma unroll
      for (int jn = 0; jn < 4; ++jn) {
        kh_[jn] = *(const bf16x8_t*)&KS[0][(jn*16 + lm) * AST + ks*32 + quad*8];
        km_[jn] = *(const bf16x8_t*)&KS[1][(jn*16 + lm) * AST + ks*32 + quad*8];
      }
      #pragma unroll
      for (int jn = 0; jn < 4; ++jn)
        sacc[jn] = __builtin_amdgcn_mfma_f32_16x16x32_bf16(qf[0][ks], kh_[jn], sacc[jn], 0,0,0);
      #pragma unroll
      for (int jn = 0; jn < 4; ++jn)
        sacc[jn] = __builtin_amdgcn_mfma_f32_16x16x32_bf16(qf[0][ks], km_[jn], sacc[jn], 0,0,0);
      #pragma unroll
      for (int jn = 0; jn < 4; ++jn)
        sacc[jn] = __builtin_amdgcn_mfma_f32_16x16x32_bf16(qf[1][ks], kh_[jn], sacc[jn], 0,0,0);
    }
    float s[4][4];
    #pragma unroll
    for (int jn = 0; jn < 4; ++jn)
      #pragma unroll
      for (int r = 0; r < 4; ++r)
        s[jn][r] = sacc[jn][r] + maskadd[kc*64 + jn*16 + lm];
    float alpha[4];
    #pragma unroll
    for (int r = 0; r < 4; ++r) {
      float rmax = fmaxf(fmaxf(s[0][r], s[1][r]), fmaxf(s[2][r], s[3][r]));
      #pragma unroll
      for (int mk = 1; mk < 16; mk <<= 1)
        rmax = fmaxf(rmax, __shfl_xor(rmax, mk, 64));
      float mnew = fmaxf(mst[r], rmax);
      alpha[r] = expf(mst[r] - mnew);
      mst[r] = mnew;
      float psum = 0.0f;
      #pragma unroll
      for (int jn = 0; jn < 4; ++jn) {
        float p = expf(s[jn][r] - mnew);
        s[jn][r] = p;
        psum += p;
      }
      #pragma unroll
      for (int mk = 1; mk < 16; mk <<= 1)
        psum += __shfl_xor(psum, mk, 64);
      lst[r] = lst[r] * alpha[r] + psum;
    }
    #pragma unroll
    for (int jn = 0; jn < 4; ++jn)
      #pragma unroll
      for (int r = 0; r < 4; ++r)
        Oacc[jn][r] *= alpha[r];
    #pragma unroll
    for (int jn = 0; jn < 4; ++jn)
      #pragma unroll
      for (int r = 0; r < 4; ++r) {
        __bf16 ph, pm, pl; split3(s[jn][r], ph, pm, pl);
        int pa = (w*16 + quad*4 + r) * AST + jn*16 + lm;
        PS[0][pa] = ph; PS[1][pa] = pm; PS[2][pa] = pl;
      }
    __syncthreads();
    #pragma unroll
    for (int ks = 0; ks < 2; ++ks) {
      bf16x8_t af[3];
      #pragma unroll
      for (int p = 0; p < 3; ++p)
        af[p] = *(const bf16x8_t*)&PS[p][(w*16 + lm) * AST + ks*32 + quad*8];
      bf16x8_t vf[3][4];
      #pragma unroll
      for (int p = 0; p < 3; ++p)
        #pragma unroll
        for (int jn = 0; jn < 4; ++jn)
          vf[p][jn] = *(const bf16x8_t*)&VS[p][(jn*16 + lm) * AST + ks*32 + quad*8];
      #pragma unroll
      for (int jn = 0; jn < 4; ++jn) {
        Oacc[jn] = __builtin_amdgcn_mfma_f32_16x16x32_bf16(af[0], vf[0][jn], Oacc[jn], 0,0,0);
        Oacc[jn] = __builtin_amdgcn_mfma_f32_16x16x32_bf16(af[0], vf[1][jn], Oacc[jn], 0,0,0);
        Oacc[jn] = __builtin_amdgcn_mfma_f32_16x16x32_bf16(af[0], vf[2][jn], Oacc[jn], 0,0,0);
        Oacc[jn] = __builtin_amdgcn_mfma_f32_16x16x32_bf16(af[1], vf[0][jn], Oacc[jn], 0,0,0);
        Oacc[jn] = __builtin_amdgcn_mfma_f32_16x16x32_bf16(af[1], vf[1][jn], Oacc[jn], 0,0,0);
        Oacc[jn] = __builtin_amdgcn_mfma_f32_16x16x32_bf16(af[2], vf[0][jn], Oacc[jn], 0,0,0);
      }
    }
    __syncthreads();
  }
  float linv[4];
  #pragma unroll
  for (int r = 0; r < 4; ++r) linv[r] = 1.0f / lst[r];
  #pragma unroll
  for (int jn = 0; jn < 4; ++jn)
    #pragma unroll
    for (int r = 0; r < 4; ++r) {
      float o = Oacc[jn][r] * linv[r];
      __bf16 hh, mm, ll; split3(o, hh, mm, ll);
      size_t oo = (size_t)(t0q + w*16 + quad*4 + r) * TD + h*64 + jn*16 + lm;
      ch[oo] = hh; cm[oo] = mm; cl[oo] = ll;
    }
}

// ---------------- LN2 + gate + routing ----------------
__global__ __launch_bounds__(256) void ln2_gate_k(const float* __restrict__ attn,
                                                  const float* __restrict__ g,
                                                  const float* __restrict__ bb,
                                                  const float* __restrict__ gw,
                                                  const float* __restrict__ gb,
                                                  __bf16* __restrict__ x2,
                                                  float* __restrict__ gates,
                                                  int* __restrict__ cnt,
                                                  int* __restrict__ tok_e,
                                                  float* __restrict__ tok_w) {
  __shared__ float red4[4];
  __shared__ float redc[4][7];
  int row = blockIdx.x, tid = threadIdx.x;
  const float* x = attn + (size_t)row * TD;
  float v0 = x[tid], v1 = x[tid + 256], v2 = x[tid + 512];
  float sum = block_sum256(v0 + v1 + v2, red4);
  float mean = sum * (1.0f / 768.0f);
  float d0 = v0 - mean, d1 = v1 - mean, d2 = v2 - mean;
  float var = block_sum256(d0*d0 + d1*d1 + d2*d2, red4) * (1.0f / 768.0f);
  float rs = rsqrtf(var + 1e-12f);
  float xn0 = g[tid]       * (d0 * rs) + bb[tid];
  float xn1 = g[tid + 256] * (d1 * rs) + bb[tid + 256];
  float xn2 = g[tid + 512] * (d2 * rs) + bb[tid + 512];
  __bf16* xo = x2 + (size_t)row * TD;
  xo[tid] = (__bf16)xn0; xo[tid + 256] = (__bf16)xn1; xo[tid + 512] = (__bf16)xn2;
  float p[7];
  const float* w0 = gw + (size_t)tid * 7;
  const float* w1p = gw + (size_t)(tid + 256) * 7;
  const float* w2p = gw + (size_t)(tid + 512) * 7;
  #pragma unroll
  for (int e = 0; e < 7; ++e) p[e] = xn0 * w0[e] + xn1 * w1p[e] + xn2 * w2p[e];
  #pragma unroll
  for (int e = 0; e < 7; ++e)
    #pragma unroll
    for (int o = 32; o > 0; o >>= 1) p[e] += __shfl_down(p[e], o, 64);
  int lane = tid & 63, wv = tid >> 6;
  if (lane == 0) {
    #pragma unroll
    for (int e = 0; e < 7; ++e) redc[wv][e] = p[e];
  }
  __syncthreads();
  if (tid == 0) {
    float l[7];
    #pragma unroll
    for (int e = 0; e < 7; ++e)
      l[e] = redc[0][e] + redc[1][e] + redc[2][e] + redc[3][e] + gb[e];
    int i1 = 0;
    for (int e = 1; e < 7; ++e) if (l[e] > l[i1]) i1 = e;
    int i2 = -1;
    for (int e = 0; e < 7; ++e) if (e != i1 && (i2 < 0 || l[e] > l[i2])) i2 = e;
    float m = l[i1];
    float e1 = expf(l[i1] - m), e2 = expf(l[i2] - m);
    float inv = 1.0f / (e1 + e2);
    float g1 = e1 * inv, g2 = e2 * inv;
    float* go = gates + (size_t)row * 7;
    #pragma unroll
    for (int e = 0; e < 7; ++e) go[e] = 0.0f;
    go[i1] = g1; go[i2] = g2;
    tok_e[row * 2] = i1; tok_e[row * 2 + 1] = i2;
    tok_w[row * 2] = g1; tok_w[row * 2 + 1] = g2;
    atomicAdd(&cnt[i1], 1);
    atomicAdd(&cnt[i2], 1);
  }
}

// ---------------- prefix ----------------
__global__ void prefix_k(const int* __restrict__ cnt, int* __restrict__ fill,
                         int* __restrict__ nrb_p, int* __restrict__ rb2e) {
  if (threadIdx.x == 0) {
    int acc = 0;
    for (int e = 0; e < TE; ++e) {
      int nb = (cnt[e] + 127) >> 7;
      fill[e] = acc * 128;
      for (int b = 0; b < nb; ++b) rb2e[acc + b] = e;
      acc += nb;
    }
    nrb_p[0] = acc;
  }
}

// ---------------- scatter (also records token->slot map) ----------------
__global__ __launch_bounds__(256) void scatter_k(const __bf16* __restrict__ x2,
                                                 const int* __restrict__ tok_e,
                                                 const float* __restrict__ tok_w,
                                                 int* __restrict__ fill,
                                                 __bf16* __restrict__ xg,
                                                 float* __restrict__ row_gw,
                                                 int* __restrict__ tok_slot) {
  int t = blockIdx.x, tid = threadIdx.x;
  __shared__ int slots[2];
  if (tid < 2) {
    int e = tok_e[t * 2 + tid];
    int s = atomicAdd(&fill[e], 1);
    slots[tid] = s;
    tok_slot[t * 2 + tid] = s;
    row_gw[s] = tok_w[t * 2 + tid];
  }
  __syncthreads();
  if (tid < 192) {
    int j = tid / 96, c = tid - j * 96;
    int s = slots[j];
    *(uint4*)(xg + (size_t)s * TD + c * 8) =
        *(const uint4*)(x2 + (size_t)t * TD + c * 8);
  }
}

// ---------------- transpose + cast fp32 -> bf16 ----------------
__global__ void transpose_cast_k(const float* __restrict__ in, __bf16* __restrict__ out,
                                 int R, int C) {
  __shared__ float tile[32][33];
  size_t zoff = (size_t)blockIdx.z * R * C;
  const float* ip = in + zoff;
  __bf16* op = out + zoff;
  int c0 = blockIdx.x * 32, r0 = blockIdx.y * 32;
  int tx = threadIdx.x, ty = threadIdx.y;
  #pragma unroll
  for (int i = 0; i < 32; i += 8)
    tile[ty + i][tx] = ip[(size_t)(r0 + ty + i) * C + c0 + tx];
  __syncthreads();
  #pragma unroll
  for (int i = 0; i < 32; i += 8)
    op[(size_t)(c0 + ty + i) * R + r0 + tx] = (__bf16)tile[tx][ty + i];
}

// ---------------- sparse FFN GEMM1 ----------------
__global__ __launch_bounds__(256) void gemm1_k(
    const __bf16* __restrict__ xg, const __bf16* __restrict__ w1T,
    const float* __restrict__ b1, const int* __restrict__ rb2e,
    const int* __restrict__ nrb_p, int cb, __bf16* __restrict__ midg)
{
  int rb = cb + blockIdx.y;
  if (rb >= nrb_p[0]) return;
  int e = rb2e[rb];
  __shared__ __align__(16) __bf16 As[4096];
  __shared__ __align__(16) __bf16 Bs[4096];
  const __bf16* A = xg + (size_t)rb * 128 * TD;
  const __bf16* BT = w1T + (size_t)e * TH * TD;
  const float* be = b1 + (size_t)e * TH;
  int n0 = blockIdx.x * 128;
  int tid = threadIdx.x;
  int wave = tid >> 6, lane = tid & 63;
  int wr = wave >> 1, wc = wave & 1;
  int lm = lane & 15, q = lane >> 4;
  f32x4_t acc[4][4];
  #pragma unroll
  for (int i = 0; i < 4; ++i)
    #pragma unroll
    for (int j = 0; j < 4; ++j) { f32x4_t z = {0.f,0.f,0.f,0.f}; acc[i][j] = z; }
  for (int k0 = 0; k0 < TD; k0 += 32) {
    #pragma unroll
    for (int it = 0; it < 2; ++it) {
      int f = it * 256 + tid; int r = f >> 2; int c8 = (f & 3) * 8;
      async16(A + (size_t)r * TD + k0 + c8, &As[f * 8]);
      async16(BT + (size_t)(n0 + r) * TD + k0 + c8, &Bs[f * 8]);
    }
    __syncthreads();
    bf16x8_t af[4], bfr[4];
    #pragma unroll
    for (int i = 0; i < 4; ++i) af[i]  = *(const bf16x8_t*)(&As[(wr*64 + i*16 + lm)*32 + q*8]);
    #pragma unroll
    for (int j = 0; j < 4; ++j) bfr[j] = *(const bf16x8_t*)(&Bs[(wc*64 + j*16 + lm)*32 + q*8]);
    #pragma unroll
    for (int i = 0; i < 4; ++i)
      #pragma unroll
      for (int j = 0; j < 4; ++j)
        acc[i][j] = __builtin_amdgcn_mfma_f32_16x16x32_bf16(af[i], bfr[j], acc[i][j], 0, 0, 0);
    __syncthreads();
  }
  #pragma unroll
  for (int i = 0; i < 4; ++i) {
    #pragma unroll
    for (int j = 0; j < 4; ++j) {
      #pragma unroll
      for (int r = 0; r < 4; ++r) {
        int row = wr*64 + i*16 + q*4 + r;
        int col = n0 + wc*64 + j*16 + lm;
        float v = acc[i][j][r] + be[col];
        v = 0.5f * v * (1.0f + erff(v * 0.70710678118654752f));
        midg[(size_t)(blockIdx.y * 128 + row) * TH + col] = (__bf16)v;
      }
    }
  }
}

// ---------------- sparse FFN GEMM2: part[slot] = gw * (mid @ w2[e] + b2[e]) ----------------
// No atomics: direct bf16 store; full K=3072 per block (no z-split).
__global__ __launch_bounds__(256) void gemm2_k(
    const __bf16* __restrict__ midg, const __bf16* __restrict__ w2T,
    const float* __restrict__ b2, const int* __restrict__ rb2e,
    const int* __restrict__ nrb_p, const float* __restrict__ row_gw,
    int cb, __bf16* __restrict__ part)
{
  int rb = cb + blockIdx.y;
  if (rb >= nrb_p[0]) return;
  int e = rb2e[rb];
  __shared__ __align__(16) __bf16 As[4096];
  __shared__ __align__(16) __bf16 Bs[4096];
  const __bf16* A = midg + (size_t)blockIdx.y * 128 * TH;
  const __bf16* BT = w2T + (size_t)e * TD * TH;
  const float* be = b2 + (size_t)e * TD;
  int n0 = blockIdx.x * 128;
  int tid = threadIdx.x;
  int wave = tid >> 6, lane = tid & 63;
  int wr = wave >> 1, wc = wave & 1;
  int lm = lane & 15, q = lane >> 4;
  f32x4_t acc[4][4];
  #pragma unroll
  for (int i = 0; i < 4; ++i)
    #pragma unroll
    for (int j = 0; j < 4; ++j) { f32x4_t z = {0.f,0.f,0.f,0.f}; acc[i][j] = z; }
  for (int k0 = 0; k0 < TH; k0 += 32) {
    #pragma unroll
    for (int it = 0; it < 2; ++it) {
      int f = it * 256 + tid; int r = f >> 2; int c8 = (f & 3) * 8;
      async16(A + (size_t)r * TH + k0 + c8, &As[f * 8]);
      async16(BT + (size_t)(n0 + r) * TH + k0 + c8, &Bs[f * 8]);
    }
    __syncthreads();
    bf16x8_t af[4], bfr[4];
    #pragma unroll
    for (int i = 0; i < 4; ++i) af[i]  = *(const bf16x8_t*)(&As[(wr*64 + i*16 + lm)*32 + q*8]);
    #pragma unroll
    for (int j = 0; j < 4; ++j) bfr[j] = *(const bf16x8_t*)(&Bs[(wc*64 + j*16 + lm)*32 + q*8]);
    #pragma unroll
    for (int i = 0; i < 4; ++i)
      #pragma unroll
      for (int j = 0; j < 4; ++j)
        acc[i][j] = __builtin_amdgcn_mfma_f32_16x16x32_bf16(af[i], bfr[j], acc[i][j], 0, 0, 0);
    __syncthreads();
  }
  #pragma unroll
  for (int i = 0; i < 4; ++i) {
    #pragma unroll
    for (int r = 0; r < 4; ++r) {
      int row = wr*64 + i*16 + q*4 + r;
      int grow = rb * 128 + row;
      float gwt = row_gw[grow];
      #pragma unroll
      for (int j = 0; j < 4; ++j) {
        int col = n0 + wc*64 + j*16 + lm;
        part[(size_t)grow * TD + col] = (__bf16)(gwt * (acc[i][j][r] + be[col]));
      }
    }
  }
}

// ---------------- gather: out[t] += part[slot0] + part[slot1] ----------------
__global__ __launch_bounds__(192) void gather_k(const __bf16* __restrict__ part,
                                                const int* __restrict__ tok_slot,
                                                float* __restrict__ outp) {
  int t = blockIdx.x, tid = threadIdx.x;
  int s0 = tok_slot[t * 2], s1 = tok_slot[t * 2 + 1];
  int c = tid * 4;
  float4 o = *(float4*)(outp + (size_t)t * TD + c);
  bf16x4_t p0 = *(const bf16x4_t*)(part + (size_t)s0 * TD + c);
  bf16x4_t p1 = *(const bf16x4_t*)(part + (size_t)s1 * TD + c);
  o.x += (float)p0[0] + (float)p1[0];
  o.y += (float)p0[1] + (float)p1[1];
  o.z += (float)p0[2] + (float)p1[2];
  o.w += (float)p0[3] + (float)p1[3];
  *(float4*)(outp + (size_t)t * TD + c) = o;
}

// ---------------- host launcher ----------------
extern "C" void kernel_launch(void* const* d_in, const int* in_sizes, int n_in,
                              void* d_out, int out_size, void* d_ws, size_t ws_size,
                              hipStream_t stream) {
  (void)in_sizes; (void)n_in; (void)out_size;
  const float* hidden = (const float*)d_in[0];
  const int*   mask   = (const int*)d_in[1];
  const float* ln1_g  = (const float*)d_in[2];
  const float* ln1_b  = (const float*)d_in[3];
  const float* wq = (const float*)d_in[4];  const float* bq = (const float*)d_in[5];
  const float* wk = (const float*)d_in[6];  const float* bk = (const float*)d_in[7];
  const float* wv = (const float*)d_in[8];  const float* bv = (const float*)d_in[9];
  const float* wo = (const float*)d_in[10]; const float* bo = (const float*)d_in[11];
  const float* gate_w = (const float*)d_in[12];
  const float* gate_b = (const float*)d_in[13];
  const float* w1 = (const float*)d_in[14];
  const float* b1 = (const float*)d_in[15];
  const float* w2 = (const float*)d_in[16];
  const float* b2 = (const float*)d_in[17];
  const float* ln2_g = (const float*)d_in[18];
  const float* ln2_b = (const float*)d_in[19];

  float* outp  = (float*)d_out;
  float* gates = (float*)d_out + (size_t)TT * TD;

  char* ws = (char*)d_ws;
  __bf16* Apl  = (__bf16*)(ws + O_APL);
  __bf16* vT0p = (__bf16*)(ws + O_VT0);
  __bf16* vT1p = (__bf16*)(ws + O_VT1);
  __bf16* vT2p = (__bf16*)(ws + O_VT2);
  __bf16* ctxh = (__bf16*)(ws + O_CTXH);
  __bf16* ctxm = (__bf16*)(ws + O_CTXM);
  __bf16* ctxl = (__bf16*)(ws + O_CTXL);
  __bf16* qkh  = (__bf16*)(ws + O_QKH);
  __bf16* qkm  = (__bf16*)(ws + O_QKM);
  float*  vcol = (float*)(ws + O_VCOL);
  __bf16* BTp  = (__bf16*)(ws + O_BT);
  __bf16* x2   = (__bf16*)(ws + O_X2);
  __bf16* xg   = (__bf16*)(ws + O_XG);   // also part[] (gemm2 output, after gemm1 consumed xg)
  __bf16* w1T  = (__bf16*)(ws + O_W1T);
  __bf16* w2T  = (__bf16*)(ws + O_W2T);
  char*   meta = ws + O_META;
  int*   cnt      = (int*)(meta + M_CNT);
  int*   fill     = (int*)(meta + M_FILL);
  int*   nrb_p    = (int*)(meta + M_NRB);
  int*   rb2e     = (int*)(meta + M_RB2E);
  int*   tok_e    = (int*)(meta + M_TOKE);
  float* tok_w    = (float*)(meta + M_TOKW);
  float* row_gw   = (float*)(meta + M_RGW);
  int*   tok_slot = (int*)(meta + M_TSLOT);
  __bf16* midg = (__bf16*)(ws + O_MIDG);

  long long midcap = (long long)ws_size - (long long)O_MIDG;
  int crb = (int)(midcap / (128LL * TH * 2));
  if (crb < 1) crb = 1;
  if (crb > NRB_MAX) crb = NRB_MAX;

  const size_t SA = (size_t)TT * TD;

  init_meta_k<<<1, 64, 0, stream>>>(cnt);
  ln1_split_k<<<TT, 256, 0, stream>>>(hidden, ln1_g, ln1_b, Apl);
  tpose_split3_k<<<dim3(24, 24, 3), dim3(32, 8), 0, stream>>>(
      wq, wk, wv, BTp, (size_t)2304 * TD, 1);
  gemm_split6_k<0><<<dim3(18, 64), 256, 0, stream>>>(
      Apl, Apl + SA, Apl + 2*SA, BTp, (size_t)2304 * TD,
      bq, bk, bv, nullptr, nullptr, qkh, qkm, vcol);
  vT_split3_k<<<dim3(16, 2, 192), dim3(32, 8), 0, stream>>>(vcol, vT0p, vT1p, vT2p);
  attn_mfma_k<<<dim3(8, TNH, TB), 256, 0, stream>>>(
      qkh, qkm, vT0p, vT1p, vT2p, mask, ctxh, ctxm, ctxl);
  tpose_split3_k<<<dim3(24, 24, 1), dim3(32, 8), 0, stream>>>(
      wo, wo, wo, BTp, (size_t)TD * TD, 0);
  gemm_split6_k<1><<<dim3(6, 64), 256, 0, stream>>>(
      ctxh, ctxm, ctxl, BTp, (size_t)TD * TD,
      bo, nullptr, nullptr, hidden, outp, nullptr, nullptr, nullptr);
  ln2_gate_k<<<TT, 256, 0, stream>>>(outp, ln2_g, ln2_b, gate_w, gate_b, x2, gates,
                                     cnt, tok_e, tok_w);
  prefix_k<<<1, 64, 0, stream>>>(cnt, fill, nrb_p, rb2e);
  scatter_k<<<TT, 256, 0, stream>>>(x2, tok_e, tok_w, fill, xg, row_gw, tok_slot);
  transpose_cast_k<<<dim3(TH / 32, TD / 32, TE), dim3(32, 8), 0, stream>>>(w1, w1T, TD, TH);
  transpose_cast_k<<<dim3(TD / 32, TH / 32, TE), dim3(32, 8), 0, stream>>>(w2, w2T, TH, TD);
  __bf16* part = xg;  // xg rows of chunk c are dead once gemm1(c) has read them
  for (int cb = 0; cb < NRB_MAX; cb += crb) {
    int nb = NRB_MAX - cb; if (nb > crb) nb = crb;
    gemm1_k<<<dim3(TH / 128, nb), 256, 0, stream>>>(xg, w1T, b1, rb2e, nrb_p, cb, midg);
    gemm2_k<<<dim3(TD / 128, nb), 256, 0, stream>>>(midg, w2T, b2, rb2e, nrb_p,
                                                    row_gw, cb, part);
  }
  gather_k<<<TT, 192, 0, stream>>>(part, tok_slot, outp);
}